// Round 1
// baseline (667.517 us; speedup 1.0000x reference)
//
#include <hip/hip_runtime.h>
#include <hip/hip_bf16.h>

#define N_NODES 20000
#define N_EDGES 320000
#define IN_CH 512
#define HID 128
#define HEADS 4
#define HC 512          // HEADS*HID
#define OUT_CH 30
#define NEG_SLOPE 0.2f

static __device__ __forceinline__ float lrelu(float e) { return e > 0.f ? e : NEG_SLOPE * e; }

// ---------------- GEMM1: h = x @ W1   [20000,512] x [512,512] ----------------
#define TM 128
#define TN 64
#define TK 32
__global__ __launch_bounds__(256) void k_gemm1(const float* __restrict__ A,
                                               const float* __restrict__ B,
                                               float* __restrict__ C) {
  __shared__ float As[TK][TM + 4];   // [k][m], pad 4 -> 132 words/row (16B aligned)
  __shared__ float Bs[TK][TN + 4];   // [k][n], 68 words/row
  const int bm = blockIdx.x * TM;
  const int bn = blockIdx.y * TN;
  const int tid = threadIdx.x;
  const int mg = tid >> 4;           // 0..15 -> owns rows mg*8..+7
  const int ng = tid & 15;           // 0..15 -> owns cols ng*4..+3
  const int lm = tid >> 3;           // A loader: 0..31
  const int lk4 = (tid & 7) * 4;     // A loader k offset
  const int lnb = (tid & 15) * 4;    // B loader n offset
  const int lkb = tid >> 4;          // B loader k row 0..15

  float acc[8][4];
#pragma unroll
  for (int i = 0; i < 8; i++)
#pragma unroll
    for (int j = 0; j < 4; j++) acc[i][j] = 0.f;

  for (int kt = 0; kt < IN_CH; kt += TK) {
#pragma unroll
    for (int c = 0; c < 4; c++) {
      int m = c * 32 + lm;
      int gm = bm + m;
      float4 v = make_float4(0.f, 0.f, 0.f, 0.f);
      if (gm < N_NODES) v = *(const float4*)(A + (size_t)gm * IN_CH + kt + lk4);
      As[lk4 + 0][m] = v.x; As[lk4 + 1][m] = v.y;
      As[lk4 + 2][m] = v.z; As[lk4 + 3][m] = v.w;
    }
#pragma unroll
    for (int c = 0; c < 2; c++) {
      int kk = c * 16 + lkb;
      float4 v = *(const float4*)(B + (size_t)(kt + kk) * HC + bn + lnb);
      *(float4*)&Bs[kk][lnb] = v;
    }
    __syncthreads();
#pragma unroll
    for (int kk = 0; kk < TK; kk++) {
      float a[8], b[4];
      *(float4*)&a[0] = *(const float4*)&As[kk][mg * 8];
      *(float4*)&a[4] = *(const float4*)&As[kk][mg * 8 + 4];
      *(float4*)&b[0] = *(const float4*)&Bs[kk][ng * 4];
#pragma unroll
      for (int i = 0; i < 8; i++)
#pragma unroll
        for (int j = 0; j < 4; j++) acc[i][j] += a[i] * b[j];
    }
    __syncthreads();
  }
#pragma unroll
  for (int i = 0; i < 8; i++) {
    int gm = bm + mg * 8 + i;
    if (gm < N_NODES)
      *(float4*)(C + (size_t)gm * HC + bn + ng * 4) = *(float4*)&acc[i][0];
  }
}

// ------------- per-node attention logits layer 1 + denom self-init ----------
__global__ __launch_bounds__(256) void k_al1(const float* __restrict__ h,
                                             const float* __restrict__ a_src,
                                             const float* __restrict__ a_dst,
                                             float* __restrict__ al_s,
                                             float* __restrict__ al_d,
                                             float* __restrict__ den) {
  const int n = blockIdx.x;
  const int head = threadIdx.x >> 6;
  const int lane = threadIdx.x & 63;
  const float* hp = h + (size_t)n * HC + head * HID;
  float2 hv = *(const float2*)(hp + lane * 2);
  float2 av = *(const float2*)(a_src + head * HID + lane * 2);
  float2 dv = *(const float2*)(a_dst + head * HID + lane * 2);
  float s = hv.x * av.x + hv.y * av.y;
  float d = hv.x * dv.x + hv.y * dv.y;
#pragma unroll
  for (int off = 32; off; off >>= 1) {
    s += __shfl_down(s, off);
    d += __shfl_down(d, off);
  }
  if (lane == 0) {
    al_s[n * HEADS + head] = s;
    al_d[n * HEADS + head] = d;
    den[n * HEADS + head] = __expf(lrelu(s + d));  // self-loop term seeds denom
  }
}

// ------------------------------- CSR build ----------------------------------
__global__ void k_zero_int(int* __restrict__ p, int n) {
  int i = blockIdx.x * blockDim.x + threadIdx.x;
  if (i < n) p[i] = 0;
}
__global__ void k_count(const int* __restrict__ dst, int* __restrict__ cnt) {
  int e = blockIdx.x * blockDim.x + threadIdx.x;
  if (e < N_EDGES) atomicAdd(&cnt[dst[e]], 1);
}
__global__ __launch_bounds__(1024) void k_scan(const int* __restrict__ cnt,
                                               int* __restrict__ offs,
                                               int* __restrict__ cursor) {
  __shared__ int buf[1024];
  __shared__ int carry;
  if (threadIdx.x == 0) carry = 0;
  __syncthreads();
  for (int base = 0; base < N_NODES; base += 1024) {
    int i = base + threadIdx.x;
    int v = (i < N_NODES) ? cnt[i] : 0;
    buf[threadIdx.x] = v;
    __syncthreads();
    for (int off = 1; off < 1024; off <<= 1) {
      int t = (threadIdx.x >= off) ? buf[threadIdx.x - off] : 0;
      __syncthreads();
      buf[threadIdx.x] += t;
      __syncthreads();
    }
    if (i < N_NODES) {
      int ex = carry + buf[threadIdx.x] - v;
      offs[i] = ex;
      cursor[i] = ex;
    }
    __syncthreads();
    if (threadIdx.x == 0) carry += buf[1023];
    __syncthreads();
  }
  if (threadIdx.x == 0) offs[N_NODES] = carry;
}
__global__ void k_scatter(const int* __restrict__ dst, int* __restrict__ cursor,
                          int* __restrict__ eid) {
  int e = blockIdx.x * blockDim.x + threadIdx.x;
  if (e < N_EDGES) {
    int pos = atomicAdd(&cursor[dst[e]], 1);
    eid[pos] = e;
  }
}

// ----------------------- edge pass layer 1 (p + denom) ----------------------
__global__ void k_edge1(const int* __restrict__ src, const int* __restrict__ dst,
                        const float* __restrict__ al_s, const float* __restrict__ al_d,
                        float* __restrict__ p1, float* __restrict__ den1) {
  int e = blockIdx.x * blockDim.x + threadIdx.x;
  if (e >= N_EDGES) return;
  int s = src[e], d = dst[e];
  float4 as = *(const float4*)(al_s + (size_t)s * 4);
  float4 ad = *(const float4*)(al_d + (size_t)d * 4);
  float4 pv;
  pv.x = __expf(lrelu(as.x + ad.x));
  pv.y = __expf(lrelu(as.y + ad.y));
  pv.z = __expf(lrelu(as.z + ad.z));
  pv.w = __expf(lrelu(as.w + ad.w));
  *(float4*)(p1 + (size_t)e * 4) = pv;
  atomicAdd(&den1[d * 4 + 0], pv.x);
  atomicAdd(&den1[d * 4 + 1], pv.y);
  atomicAdd(&den1[d * 4 + 2], pv.z);
  atomicAdd(&den1[d * 4 + 3], pv.w);
}

// ------------------- aggregation layer 1 + bias + ELU -----------------------
__global__ __launch_bounds__(256) void k_agg1(const float* __restrict__ h,
                                              const float* __restrict__ p1,
                                              const float* __restrict__ den1,
                                              const float* __restrict__ al_s,
                                              const float* __restrict__ al_d,
                                              const int* __restrict__ offs,
                                              const int* __restrict__ eid,
                                              const int* __restrict__ srcv,
                                              const float* __restrict__ b1,
                                              float* __restrict__ hm) {
  const int n = blockIdx.x;
  const int tid = threadIdx.x;
  const int head = tid >> 6;      // wave-uniform (c = tid*2, head = c>>7)
  __shared__ float inv_den[HEADS];
  __shared__ float pself[HEADS];
  if (tid < HEADS) {
    inv_den[tid] = 1.f / den1[n * HEADS + tid];
    pself[tid] = __expf(lrelu(al_s[n * HEADS + tid] + al_d[n * HEADS + tid]));
  }
  __syncthreads();
  const int c = tid * 2;
  const float invd = inv_den[head];
  float2 hv = *(const float2*)(h + (size_t)n * HC + c);
  float a0 = pself[head] * invd;
  float accx = a0 * hv.x, accy = a0 * hv.y;
  const int beg = offs[n], end = offs[n + 1];
  for (int q = beg; q < end; q++) {
    int e = eid[q];
    int s = srcv[e];
    float alpha = p1[(size_t)e * 4 + head] * invd;
    float2 v = *(const float2*)(h + (size_t)s * HC + c);
    accx += alpha * v.x;
    accy += alpha * v.y;
  }
  float2 bb = *(const float2*)(b1 + c);
  float o0 = accx + bb.x, o1 = accy + bb.y;
  o0 = o0 > 0.f ? o0 : __expf(o0) - 1.f;   // ELU (alpha=1)
  o1 = o1 > 0.f ? o1 : __expf(o1) - 1.f;
  *(float2*)(hm + (size_t)n * HC + c) = make_float2(o0, o1);
}

// ---------------- GEMM2: zpre = hm @ W2  [20000,512] x [512,30] -------------
#define G2_TM 64
#define G2_TK 64
__global__ __launch_bounds__(256) void k_gemm2(const float* __restrict__ A,
                                               const float* __restrict__ W2,
                                               float* __restrict__ zpre) {
  __shared__ float As[G2_TM][G2_TK + 4];
  __shared__ float Ws[G2_TK][32];
  const int bm = blockIdx.x * G2_TM;
  const int tid = threadIdx.x;
  const int mg = tid >> 4;   // 0..15 -> rows mg*4..+3
  const int cg = tid & 15;   // c = cg*2
  const int lr = tid >> 4;   // loader row
  const int lc = (tid & 15) * 4;
  float acc[4][2] = {};
  for (int kt = 0; kt < HC; kt += G2_TK) {
#pragma unroll
    for (int p = 0; p < 4; p++) {
      int m = p * 16 + lr;
      int gm = bm + m;
      float4 v = make_float4(0.f, 0.f, 0.f, 0.f);
      if (gm < N_NODES) v = *(const float4*)(A + (size_t)gm * HC + kt + lc);
      *(float4*)&As[m][lc] = v;
    }
    for (int idx = tid; idx < G2_TK * 32; idx += 256) {
      int r = idx >> 5, c = idx & 31;
      Ws[r][c] = (c < OUT_CH) ? W2[(size_t)(kt + r) * OUT_CH + c] : 0.f;
    }
    __syncthreads();
#pragma unroll
    for (int kk = 0; kk < G2_TK; kk++) {
      float b0 = Ws[kk][cg * 2];
      float b1v = Ws[kk][cg * 2 + 1];
#pragma unroll
      for (int i = 0; i < 4; i++) {
        float a = As[mg * 4 + i][kk];
        acc[i][0] += a * b0;
        acc[i][1] += a * b1v;
      }
    }
    __syncthreads();
  }
  const int c = cg * 2;
  if (c < OUT_CH) {
#pragma unroll
    for (int i = 0; i < 4; i++) {
      int gm = bm + mg * 4 + i;
      if (gm < N_NODES)
        *(float2*)(zpre + (size_t)gm * OUT_CH + c) = make_float2(acc[i][0], acc[i][1]);
    }
  }
}

// ------------- layer-2 logits + denom self-init (1 head, C=30) --------------
__global__ void k_al2(const float* __restrict__ zpre, const float* __restrict__ a_s,
                      const float* __restrict__ a_d, float* __restrict__ al_s2,
                      float* __restrict__ al_d2, float* __restrict__ den2) {
  int n = blockIdx.x * blockDim.x + threadIdx.x;
  if (n >= N_NODES) return;
  const float* z = zpre + (size_t)n * OUT_CH;
  float s = 0.f, d = 0.f;
#pragma unroll
  for (int c = 0; c < OUT_CH; c++) {
    float v = z[c];
    s += v * a_s[c];
    d += v * a_d[c];
  }
  al_s2[n] = s;
  al_d2[n] = d;
  den2[n] = __expf(lrelu(s + d));
}

__global__ void k_edge2(const int* __restrict__ src, const int* __restrict__ dst,
                        const float* __restrict__ al_s2, const float* __restrict__ al_d2,
                        float* __restrict__ p2, float* __restrict__ den2) {
  int e = blockIdx.x * blockDim.x + threadIdx.x;
  if (e >= N_EDGES) return;
  int s = src[e], d = dst[e];
  float p = __expf(lrelu(al_s2[s] + al_d2[d]));
  p2[e] = p;
  atomicAdd(&den2[d], p);
}

// ------------------- aggregation layer 2 + bias -> z (d_out) ----------------
__global__ __launch_bounds__(256) void k_agg2(const float* __restrict__ zpre,
                                              const float* __restrict__ p2,
                                              const float* __restrict__ den2,
                                              const float* __restrict__ al_s2,
                                              const float* __restrict__ al_d2,
                                              const int* __restrict__ offs,
                                              const int* __restrict__ eid,
                                              const int* __restrict__ srcv,
                                              const float* __restrict__ b2,
                                              float* __restrict__ zout) {
  const int n = blockIdx.x * 4 + (threadIdx.x >> 6);
  const int lane = threadIdx.x & 63;
  if (n >= N_NODES) return;
  const float invd = 1.f / den2[n];
  const float pself = __expf(lrelu(al_s2[n] + al_d2[n]));
  float v = (lane < OUT_CH) ? zpre[(size_t)n * OUT_CH + lane] : 0.f;
  float acc = pself * invd * v;
  const int beg = offs[n], end = offs[n + 1];
  for (int q = beg; q < end; q++) {
    int e = eid[q];
    int s = srcv[e];
    float alpha = p2[e] * invd;
    float sv = (lane < OUT_CH) ? zpre[(size_t)s * OUT_CH + lane] : 0.f;
    acc += alpha * sv;
  }
  if (lane < OUT_CH) zout[(size_t)n * OUT_CH + lane] = acc + b2[lane];
}

// ---------------- decoder: x_hat = z @ Wd + bd  [20000,30]x[30,512] ---------
__global__ __launch_bounds__(256) void k_dec(const float* __restrict__ z,
                                             const float* __restrict__ Wd,
                                             const float* __restrict__ bd,
                                             float* __restrict__ xhat) {
  __shared__ float Wds[OUT_CH * IN_CH];  // 61440 B
  __shared__ float zs[16][32];           // 2048 B
  const int tid = threadIdx.x;
  for (int idx = tid; idx < OUT_CH * IN_CH; idx += 256) Wds[idx] = Wd[idx];
  const int n0 = blockIdx.x * 16;
  for (int idx = tid; idx < 16 * 32; idx += 256) {
    int r = idx >> 5, c = idx & 31;
    zs[r][c] = (c < OUT_CH) ? z[(size_t)(n0 + r) * OUT_CH + c] : 0.f;
  }
  __syncthreads();
  const int c = tid * 2;
  const float b0 = bd[c], b1v = bd[c + 1];
#pragma unroll 4
  for (int i = 0; i < 16; i++) {
    float a0 = b0, a1 = b1v;
#pragma unroll
    for (int k = 0; k < OUT_CH; k++) {
      float zv = zs[i][k];
      a0 += zv * Wds[k * IN_CH + c];
      a1 += zv * Wds[k * IN_CH + c + 1];
    }
    *(float2*)(xhat + (size_t)(n0 + i) * IN_CH + c) = make_float2(a0, a1);
  }
}

// ----------------------------------------------------------------------------
extern "C" void kernel_launch(void* const* d_in, const int* in_sizes, int n_in,
                              void* d_out, int out_size, void* d_ws, size_t ws_size,
                              hipStream_t stream) {
  const float* x    = (const float*)d_in[0];
  const int*   ei   = (const int*)d_in[1];
  const float* W1   = (const float*)d_in[2];
  const float* a_s1 = (const float*)d_in[3];
  const float* a_d1 = (const float*)d_in[4];
  const float* b1   = (const float*)d_in[5];
  const float* W2   = (const float*)d_in[6];
  const float* a_s2 = (const float*)d_in[7];
  const float* a_d2 = (const float*)d_in[8];
  const float* b2   = (const float*)d_in[9];
  const float* Wd   = (const float*)d_in[10];
  const float* bd   = (const float*)d_in[11];

  float* xhat = (float*)d_out;
  float* zout = xhat + (size_t)N_NODES * IN_CH;

  const int* srcv = ei;
  const int* dstv = ei + N_EDGES;

  char* w = (char*)d_ws;
  auto alloc = [&](size_t bytes) {
    void* p = (void*)w;
    w += (bytes + 255) & ~(size_t)255;
    return p;
  };
  float* h     = (float*)alloc((size_t)N_NODES * HC * 4);
  float* hm    = (float*)alloc((size_t)N_NODES * HC * 4);
  float* zpre  = (float*)alloc((size_t)N_NODES * OUT_CH * 4);
  float* al_s1v= (float*)alloc((size_t)N_NODES * HEADS * 4);
  float* al_d1v= (float*)alloc((size_t)N_NODES * HEADS * 4);
  float* den1  = (float*)alloc((size_t)N_NODES * HEADS * 4);
  float* p1    = (float*)alloc((size_t)N_EDGES * HEADS * 4);
  float* al_s2v= (float*)alloc((size_t)N_NODES * 4);
  float* al_d2v= (float*)alloc((size_t)N_NODES * 4);
  float* den2  = (float*)alloc((size_t)N_NODES * 4);
  float* p2    = (float*)alloc((size_t)N_EDGES * 4);
  int*   cnt   = (int*)alloc((size_t)N_NODES * 4);
  int*   offs  = (int*)alloc((size_t)(N_NODES + 1) * 4);
  int*   cursor= (int*)alloc((size_t)N_NODES * 4);
  int*   eidb  = (int*)alloc((size_t)N_EDGES * 4);

  const int EB = (N_EDGES + 255) / 256;
  const int NB = (N_NODES + 255) / 256;

  // GEMM1
  k_gemm1<<<dim3((N_NODES + TM - 1) / TM, HC / TN), 256, 0, stream>>>(x, W1, h);
  // attention logits layer 1 (+ denom self-seed)
  k_al1<<<N_NODES, 256, 0, stream>>>(h, a_s1, a_d1, al_s1v, al_d1v, den1);
  // CSR build
  k_zero_int<<<NB, 256, 0, stream>>>(cnt, N_NODES);
  k_count<<<EB, 256, 0, stream>>>(dstv, cnt);
  k_scan<<<1, 1024, 0, stream>>>(cnt, offs, cursor);
  k_scatter<<<EB, 256, 0, stream>>>(dstv, cursor, eidb);
  // edge softmax numerators + denoms
  k_edge1<<<EB, 256, 0, stream>>>(srcv, dstv, al_s1v, al_d1v, p1, den1);
  // aggregate + bias + ELU
  k_agg1<<<N_NODES, 256, 0, stream>>>(h, p1, den1, al_s1v, al_d1v, offs, eidb, srcv, b1, hm);
  // GEMM2
  k_gemm2<<<(N_NODES + G2_TM - 1) / G2_TM, 256, 0, stream>>>(hm, W2, zpre);
  // layer-2 attention
  k_al2<<<NB, 256, 0, stream>>>(zpre, a_s2, a_d2, al_s2v, al_d2v, den2);
  k_edge2<<<EB, 256, 0, stream>>>(srcv, dstv, al_s2v, al_d2v, p2, den2);
  k_agg2<<<(N_NODES + 3) / 4, 256, 0, stream>>>(zpre, p2, den2, al_s2v, al_d2v, offs, eidb,
                                                srcv, b2, zout);
  // decoder
  k_dec<<<N_NODES / 16, 256, 0, stream>>>(zout, Wd, bd, xhat);
}

// Round 2
// 487.005 us; speedup vs baseline: 1.3707x; 1.3707x over previous
//
#include <hip/hip_runtime.h>
#include <hip/hip_bf16.h>
#include <stdint.h>

#define N_NODES 20000
#define N_EDGES 320000
#define IN_CH 512
#define HID 128
#define HEADS 4
#define HC 512          // HEADS*HID
#define OUT_CH 30
#define NEG_SLOPE 0.2f
#define M_PAD 20096     // 157 * 128

typedef _Float16 half8 __attribute__((ext_vector_type(8)));
typedef _Float16 half4v __attribute__((ext_vector_type(4)));
typedef float f32x4 __attribute__((ext_vector_type(4)));

static __device__ __forceinline__ float lrelu(float e) { return e > 0.f ? e : NEG_SLOPE * e; }

// async global->LDS, 16B per lane; dest = wave-uniform base + lane*16
static __device__ __forceinline__ void gload16(const void* gsrc, void* ldst) {
  __builtin_amdgcn_global_load_lds(
      (const __attribute__((address_space(1))) uint32_t*)gsrc,
      (__attribute__((address_space(3))) uint32_t*)ldst,
      16, 0, 0);
}

// ------------------------- cast x -> fp16 (padded rows zeroed) ---------------
__global__ __launch_bounds__(256) void k_cast_x(const float* __restrict__ x,
                                                _Float16* __restrict__ xh) {
  int i = blockIdx.x * blockDim.x + threadIdx.x;   // quad index over M_PAD*512/4
  int base = i * 4;
  int row = base >> 9;
  half4v o;
  if (row < N_NODES) {
    float4 v = *(const float4*)(x + (size_t)base);
    o[0] = (_Float16)v.x; o[1] = (_Float16)v.y; o[2] = (_Float16)v.z; o[3] = (_Float16)v.w;
  } else {
    o[0] = o[1] = o[2] = o[3] = (_Float16)0.f;
  }
  *(half4v*)(xh + (size_t)base) = o;
}

// ------------------- cast + transpose W1 [k][n] -> W1t fp16 [n][k] ----------
__global__ __launch_bounds__(256) void k_cast_w1t(const float* __restrict__ W1,
                                                  _Float16* __restrict__ W1t) {
  __shared__ float t[64][65];
  const int bk = blockIdx.x * 64;
  const int bn = blockIdx.y * 64;
  const int tid = threadIdx.x;
#pragma unroll
  for (int it = 0; it < 16; it++) {
    int idx = tid + it * 256;
    int r = idx >> 6, c = idx & 63;
    t[r][c] = W1[(size_t)(bk + r) * HC + bn + c];
  }
  __syncthreads();
#pragma unroll
  for (int it = 0; it < 16; it++) {
    int idx = tid + it * 256;
    int rn = idx >> 6, ck = idx & 63;
    W1t[(size_t)(bn + rn) * IN_CH + bk + ck] = (_Float16)t[ck][rn];
  }
}

// ---------------- GEMM1 (MFMA fp16): h = x @ W1  [M_PAD,512]x[512,512] ------
// A = xh [M_PAD][512] fp16, Bt = W1t [512][512] fp16 (n-major). 128x128 tile, BK=64.
__global__ __launch_bounds__(256) void k_gemm1_mfma(const _Float16* __restrict__ A,
                                                    const _Float16* __restrict__ Bt,
                                                    float* __restrict__ C) {
  __shared__ _Float16 As[128 * 64];
  __shared__ _Float16 Bs[128 * 64];
  const int tid = threadIdx.x;
  const int lane = tid & 63;
  const int w = tid >> 6;
  const int bm = blockIdx.x * 128;
  const int bn = blockIdx.y * 128;

  // staging addressing: inst t covers rows w*32 + t*8 + (lane>>3); slot lane&7,
  // source chunk XOR-swizzled by row&7 so ds_read lands conflict-free
  const int lrow = lane >> 3;
  const int schunk = (lane & 7) ^ lrow;

  const int wm = w >> 1, wn = w & 1;
  const int r15 = lane & 15;
  const int q = lane >> 4;
  const int a_row0 = wm * 64 + r15;
  const int b_row0 = wn * 64 + r15;

  f32x4 acc[4][4];
  const f32x4 zero = {0.f, 0.f, 0.f, 0.f};
#pragma unroll
  for (int i = 0; i < 4; i++)
#pragma unroll
    for (int j = 0; j < 4; j++) acc[i][j] = zero;

  for (int kb = 0; kb < 8; kb++) {
    const int kof = kb * 64 + schunk * 8;
#pragma unroll
    for (int t = 0; t < 4; t++) {
      const int row = w * 32 + t * 8;
      gload16(A + (size_t)(bm + row + lrow) * IN_CH + kof, (void*)(As + row * 64));
      gload16(Bt + (size_t)(bn + row + lrow) * IN_CH + kof, (void*)(Bs + row * 64));
    }
    __syncthreads();
#pragma unroll
    for (int s = 0; s < 2; s++) {
      const int cs = ((s * 4 + q) ^ (lane & 7)) * 8;
      half8 af[4], bf[4];
#pragma unroll
      for (int i = 0; i < 4; i++) af[i] = *(const half8*)&As[(a_row0 + i * 16) * 64 + cs];
#pragma unroll
      for (int j = 0; j < 4; j++) bf[j] = *(const half8*)&Bs[(b_row0 + j * 16) * 64 + cs];
#pragma unroll
      for (int i = 0; i < 4; i++)
#pragma unroll
        for (int j = 0; j < 4; j++)
          acc[i][j] = __builtin_amdgcn_mfma_f32_16x16x32_f16(af[i], bf[j], acc[i][j], 0, 0, 0);
    }
    __syncthreads();
  }
  // epilogue: C/D layout col=lane&15, row=(lane>>4)*4+reg
#pragma unroll
  for (int i = 0; i < 4; i++) {
#pragma unroll
    for (int j = 0; j < 4; j++) {
      const int gn = bn + wn * 64 + j * 16 + r15;
#pragma unroll
      for (int r = 0; r < 4; r++) {
        const int gm = bm + wm * 64 + i * 16 + q * 4 + r;
        if (gm < N_NODES) C[(size_t)gm * HC + gn] = acc[i][j][r];
      }
    }
  }
}

// ------------- per-node attention logits layer 1 + denom self-init ----------
__global__ __launch_bounds__(256) void k_al1(const float* __restrict__ h,
                                             const float* __restrict__ a_src,
                                             const float* __restrict__ a_dst,
                                             float* __restrict__ al_s,
                                             float* __restrict__ al_d,
                                             float* __restrict__ den) {
  const int n = blockIdx.x;
  const int head = threadIdx.x >> 6;
  const int lane = threadIdx.x & 63;
  const float* hp = h + (size_t)n * HC + head * HID;
  float2 hv = *(const float2*)(hp + lane * 2);
  float2 av = *(const float2*)(a_src + head * HID + lane * 2);
  float2 dv = *(const float2*)(a_dst + head * HID + lane * 2);
  float s = hv.x * av.x + hv.y * av.y;
  float d = hv.x * dv.x + hv.y * dv.y;
#pragma unroll
  for (int off = 32; off; off >>= 1) {
    s += __shfl_down(s, off);
    d += __shfl_down(d, off);
  }
  if (lane == 0) {
    al_s[n * HEADS + head] = s;
    al_d[n * HEADS + head] = d;
    den[n * HEADS + head] = __expf(lrelu(s + d));  // self-loop seeds denom
  }
}

// ------------------------------- CSR build ----------------------------------
#define PARTS 79   // ceil(20000/256)
__global__ void k_zero_int(int* __restrict__ p, int n) {
  int i = blockIdx.x * blockDim.x + threadIdx.x;
  if (i < n) p[i] = 0;
}
__global__ void k_count(const int* __restrict__ dst, int* __restrict__ cnt) {
  int e = blockIdx.x * blockDim.x + threadIdx.x;
  if (e < N_EDGES) atomicAdd(&cnt[dst[e]], 1);
}
__global__ __launch_bounds__(256) void k_scan_part(const int* __restrict__ cnt,
                                                   int* __restrict__ part) {
  __shared__ int ws[4];
  int i = blockIdx.x * 256 + threadIdx.x;
  int v = (i < N_NODES) ? cnt[i] : 0;
  int lane = threadIdx.x & 63;
#pragma unroll
  for (int off = 32; off; off >>= 1) v += __shfl_down(v, off);
  if (lane == 0) ws[threadIdx.x >> 6] = v;
  __syncthreads();
  if (threadIdx.x == 0) part[blockIdx.x] = ws[0] + ws[1] + ws[2] + ws[3];
}
__global__ __launch_bounds__(128) void k_scan_tops(int* __restrict__ part,
                                                   int* __restrict__ offs) {
  __shared__ int buf[128];
  int t = threadIdx.x;
  int v = (t < PARTS) ? part[t] : 0;
  buf[t] = v;
  __syncthreads();
#pragma unroll
  for (int off = 1; off < 128; off <<= 1) {
    int x = (t >= off) ? buf[t - off] : 0;
    __syncthreads();
    buf[t] += x;
    __syncthreads();
  }
  if (t < PARTS) part[t] = buf[t] - v;        // exclusive
  if (t == PARTS - 1) offs[N_NODES] = buf[t]; // total
}
__global__ __launch_bounds__(256) void k_scan_final(const int* __restrict__ cnt,
                                                    const int* __restrict__ part,
                                                    int* __restrict__ offs,
                                                    int* __restrict__ cursor) {
  __shared__ int buf[256];
  int i = blockIdx.x * 256 + threadIdx.x;
  int t = threadIdx.x;
  int v = (i < N_NODES) ? cnt[i] : 0;
  buf[t] = v;
  __syncthreads();
#pragma unroll
  for (int off = 1; off < 256; off <<= 1) {
    int x = (t >= off) ? buf[t - off] : 0;
    __syncthreads();
    buf[t] += x;
    __syncthreads();
  }
  if (i < N_NODES) {
    int ex = part[blockIdx.x] + buf[t] - v;
    offs[i] = ex;
    cursor[i] = ex;
  }
}
__global__ void k_scatter(const int* __restrict__ dst, int* __restrict__ cursor,
                          int* __restrict__ eid) {
  int e = blockIdx.x * blockDim.x + threadIdx.x;
  if (e < N_EDGES) {
    int pos = atomicAdd(&cursor[dst[e]], 1);
    eid[pos] = e;
  }
}

// ----------------------- edge pass layer 1 (p + denom) ----------------------
__global__ void k_edge1(const int* __restrict__ src, const int* __restrict__ dst,
                        const float* __restrict__ al_s, const float* __restrict__ al_d,
                        float* __restrict__ p1, float* __restrict__ den1) {
  int e = blockIdx.x * blockDim.x + threadIdx.x;
  if (e >= N_EDGES) return;
  int s = src[e], d = dst[e];
  float4 as = *(const float4*)(al_s + (size_t)s * 4);
  float4 ad = *(const float4*)(al_d + (size_t)d * 4);
  float4 pv;
  pv.x = __expf(lrelu(as.x + ad.x));
  pv.y = __expf(lrelu(as.y + ad.y));
  pv.z = __expf(lrelu(as.z + ad.z));
  pv.w = __expf(lrelu(as.w + ad.w));
  *(float4*)(p1 + (size_t)e * 4) = pv;
  atomicAdd(&den1[d * 4 + 0], pv.x);
  atomicAdd(&den1[d * 4 + 1], pv.y);
  atomicAdd(&den1[d * 4 + 2], pv.z);
  atomicAdd(&den1[d * 4 + 3], pv.w);
}

// ------------------- aggregation layer 1 + bias + ELU -----------------------
__global__ __launch_bounds__(256) void k_agg1(const float* __restrict__ h,
                                              const float* __restrict__ p1,
                                              const float* __restrict__ den1,
                                              const float* __restrict__ al_s,
                                              const float* __restrict__ al_d,
                                              const int* __restrict__ offs,
                                              const int* __restrict__ eid,
                                              const int* __restrict__ srcv,
                                              const float* __restrict__ b1,
                                              float* __restrict__ hm) {
  const int n = blockIdx.x;
  const int tid = threadIdx.x;
  const int head = tid >> 6;      // wave-uniform
  __shared__ float inv_den[HEADS];
  __shared__ float pself[HEADS];
  __shared__ int s_src[64];
  __shared__ float s_al[HEADS][64];
  if (tid < HEADS) {
    inv_den[tid] = 1.f / den1[n * HEADS + tid];
    pself[tid] = __expf(lrelu(al_s[n * HEADS + tid] + al_d[n * HEADS + tid]));
  }
  __syncthreads();
  const int c = tid * 2;
  const float invd = inv_den[head];
  float2 hv = *(const float2*)(h + (size_t)n * HC + c);
  float a0 = pself[head] * invd;
  float accx = a0 * hv.x, accy = a0 * hv.y;
  const int beg = offs[n], end = offs[n + 1];
  for (int base = beg; base < end; base += 64) {
    int m = min(64, end - base);
    if (tid < m) {
      int e = eid[base + tid];
      s_src[tid] = srcv[e];
      float4 pv = *(const float4*)(p1 + (size_t)e * 4);
      s_al[0][tid] = pv.x; s_al[1][tid] = pv.y; s_al[2][tid] = pv.z; s_al[3][tid] = pv.w;
    }
    __syncthreads();
    for (int qq = 0; qq < m; qq++) {
      float alpha = s_al[head][qq] * invd;   // wave-uniform broadcast
      float2 v = *(const float2*)(h + (size_t)s_src[qq] * HC + c);
      accx += alpha * v.x;
      accy += alpha * v.y;
    }
    __syncthreads();
  }
  float2 bb = *(const float2*)(b1 + c);
  float o0 = accx + bb.x, o1 = accy + bb.y;
  o0 = o0 > 0.f ? o0 : __expf(o0) - 1.f;   // ELU
  o1 = o1 > 0.f ? o1 : __expf(o1) - 1.f;
  *(float2*)(hm + (size_t)n * HC + c) = make_float2(o0, o1);
}

// ---------------- GEMM2: zpre = hm @ W2  [20000,512] x [512,30] -------------
#define G2_TM 64
#define G2_TK 64
__global__ __launch_bounds__(256) void k_gemm2(const float* __restrict__ A,
                                               const float* __restrict__ W2,
                                               float* __restrict__ zpre) {
  __shared__ float As[G2_TM][G2_TK + 4];
  __shared__ float Ws[G2_TK][32];
  const int bm = blockIdx.x * G2_TM;
  const int tid = threadIdx.x;
  const int mg = tid >> 4;
  const int cg = tid & 15;
  const int lr = tid >> 4;
  const int lc = (tid & 15) * 4;
  float acc[4][2] = {};
  for (int kt = 0; kt < HC; kt += G2_TK) {
#pragma unroll
    for (int p = 0; p < 4; p++) {
      int m = p * 16 + lr;
      int gm = bm + m;
      float4 v = make_float4(0.f, 0.f, 0.f, 0.f);
      if (gm < N_NODES) v = *(const float4*)(A + (size_t)gm * HC + kt + lc);
      *(float4*)&As[m][lc] = v;
    }
    for (int idx = tid; idx < G2_TK * 32; idx += 256) {
      int r = idx >> 5, c = idx & 31;
      Ws[r][c] = (c < OUT_CH) ? W2[(size_t)(kt + r) * OUT_CH + c] : 0.f;
    }
    __syncthreads();
#pragma unroll
    for (int kk = 0; kk < G2_TK; kk++) {
      float b0 = Ws[kk][cg * 2];
      float b1v = Ws[kk][cg * 2 + 1];
#pragma unroll
      for (int i = 0; i < 4; i++) {
        float a = As[mg * 4 + i][kk];
        acc[i][0] += a * b0;
        acc[i][1] += a * b1v;
      }
    }
    __syncthreads();
  }
  const int c = cg * 2;
  if (c < OUT_CH) {
#pragma unroll
    for (int i = 0; i < 4; i++) {
      int gm = bm + mg * 4 + i;
      if (gm < N_NODES)
        *(float2*)(zpre + (size_t)gm * OUT_CH + c) = make_float2(acc[i][0], acc[i][1]);
    }
  }
}

// ------------- layer-2 logits + denom self-init (1 head, C=30) --------------
__global__ void k_al2(const float* __restrict__ zpre, const float* __restrict__ a_s,
                      const float* __restrict__ a_d, float* __restrict__ al_s2,
                      float* __restrict__ al_d2, float* __restrict__ den2) {
  int n = blockIdx.x * blockDim.x + threadIdx.x;
  if (n >= N_NODES) return;
  const float* z = zpre + (size_t)n * OUT_CH;
  float s = 0.f, d = 0.f;
#pragma unroll
  for (int c = 0; c < OUT_CH; c++) {
    float v = z[c];
    s += v * a_s[c];
    d += v * a_d[c];
  }
  al_s2[n] = s;
  al_d2[n] = d;
  den2[n] = __expf(lrelu(s + d));
}

__global__ void k_edge2(const int* __restrict__ src, const int* __restrict__ dst,
                        const float* __restrict__ al_s2, const float* __restrict__ al_d2,
                        float* __restrict__ p2, float* __restrict__ den2) {
  int e = blockIdx.x * blockDim.x + threadIdx.x;
  if (e >= N_EDGES) return;
  int s = src[e], d = dst[e];
  float p = __expf(lrelu(al_s2[s] + al_d2[d]));
  p2[e] = p;
  atomicAdd(&den2[d], p);
}

// ------------------- aggregation layer 2 + bias -> z (d_out) ----------------
__global__ __launch_bounds__(256) void k_agg2(const float* __restrict__ zpre,
                                              const float* __restrict__ p2,
                                              const float* __restrict__ den2,
                                              const float* __restrict__ al_s2,
                                              const float* __restrict__ al_d2,
                                              const int* __restrict__ offs,
                                              const int* __restrict__ eid,
                                              const int* __restrict__ srcv,
                                              const float* __restrict__ b2,
                                              float* __restrict__ zout) {
  const int n = blockIdx.x * 4 + (threadIdx.x >> 6);
  const int lane = threadIdx.x & 63;
  if (n >= N_NODES) return;
  const float invd = 1.f / den2[n];
  const float pself = __expf(lrelu(al_s2[n] + al_d2[n]));
  float v = (lane < OUT_CH) ? zpre[(size_t)n * OUT_CH + lane] : 0.f;
  float acc = pself * invd * v;
  const int beg = offs[n], end = offs[n + 1];
  for (int base = beg; base < end; base += 64) {
    int m = min(64, end - base);
    int e = (lane < m) ? eid[base + lane] : 0;
    int ssrc = (lane < m) ? srcv[e] : 0;
    float pp = (lane < m) ? p2[e] : 0.f;
    for (int qq = 0; qq < m; qq++) {
      int s = __shfl(ssrc, qq);
      float alpha = __shfl(pp, qq) * invd;
      float sv = (lane < OUT_CH) ? zpre[(size_t)s * OUT_CH + lane] : 0.f;
      acc += alpha * sv;
    }
  }
  if (lane < OUT_CH) zout[(size_t)n * OUT_CH + lane] = acc + b2[lane];
}

// ---------------- decoder: x_hat = z @ Wd + bd  [20000,30]x[30,512] ---------
__global__ __launch_bounds__(256) void k_dec(const float* __restrict__ z,
                                             const float* __restrict__ Wd,
                                             const float* __restrict__ bd,
                                             float* __restrict__ xhat) {
  __shared__ float Wds[OUT_CH * IN_CH];  // 61440 B
  __shared__ float zs[16][32];
  const int tid = threadIdx.x;
  for (int idx = tid; idx < OUT_CH * IN_CH; idx += 256) Wds[idx] = Wd[idx];
  const int n0 = blockIdx.x * 16;
  for (int idx = tid; idx < 16 * 32; idx += 256) {
    int r = idx >> 5, c = idx & 31;
    zs[r][c] = (c < OUT_CH) ? z[(size_t)(n0 + r) * OUT_CH + c] : 0.f;
  }
  __syncthreads();
  const int c = tid * 2;
  const float b0 = bd[c], b1v = bd[c + 1];
#pragma unroll 4
  for (int i = 0; i < 16; i++) {
    float a0 = b0, a1 = b1v;
#pragma unroll
    for (int k = 0; k < OUT_CH; k++) {
      float zv = zs[i][k];
      a0 += zv * Wds[k * IN_CH + c];
      a1 += zv * Wds[k * IN_CH + c + 1];
    }
    *(float2*)(xhat + (size_t)(n0 + i) * IN_CH + c) = make_float2(a0, a1);
  }
}

// ----------------------------------------------------------------------------
extern "C" void kernel_launch(void* const* d_in, const int* in_sizes, int n_in,
                              void* d_out, int out_size, void* d_ws, size_t ws_size,
                              hipStream_t stream) {
  const float* x    = (const float*)d_in[0];
  const int*   ei   = (const int*)d_in[1];
  const float* W1   = (const float*)d_in[2];
  const float* a_s1 = (const float*)d_in[3];
  const float* a_d1 = (const float*)d_in[4];
  const float* b1   = (const float*)d_in[5];
  const float* W2   = (const float*)d_in[6];
  const float* a_s2 = (const float*)d_in[7];
  const float* a_d2 = (const float*)d_in[8];
  const float* b2   = (const float*)d_in[9];
  const float* Wd   = (const float*)d_in[10];
  const float* bd   = (const float*)d_in[11];

  float* xhat = (float*)d_out;
  float* zout = xhat + (size_t)N_NODES * IN_CH;

  const int* srcv = ei;
  const int* dstv = ei + N_EDGES;

  char* w = (char*)d_ws;
  auto alloc = [&](size_t bytes) {
    void* p = (void*)w;
    w += (bytes + 255) & ~(size_t)255;
    return p;
  };
  _Float16* xh   = (_Float16*)alloc((size_t)M_PAD * IN_CH * 2);
  _Float16* w1t  = (_Float16*)alloc((size_t)HC * IN_CH * 2);
  float* h     = (float*)alloc((size_t)N_NODES * HC * 4);
  float* hm    = (float*)alloc((size_t)N_NODES * HC * 4);
  float* zpre  = (float*)alloc((size_t)N_NODES * OUT_CH * 4);
  float* al_s1v= (float*)alloc((size_t)N_NODES * HEADS * 4);
  float* al_d1v= (float*)alloc((size_t)N_NODES * HEADS * 4);
  float* den1  = (float*)alloc((size_t)N_NODES * HEADS * 4);
  float* p1    = (float*)alloc((size_t)N_EDGES * HEADS * 4);
  float* al_s2v= (float*)alloc((size_t)N_NODES * 4);
  float* al_d2v= (float*)alloc((size_t)N_NODES * 4);
  float* den2  = (float*)alloc((size_t)N_NODES * 4);
  float* p2    = (float*)alloc((size_t)N_EDGES * 4);
  int*   cnt   = (int*)alloc((size_t)N_NODES * 4);
  int*   offs  = (int*)alloc((size_t)(N_NODES + 1) * 4);
  int*   cursor= (int*)alloc((size_t)N_NODES * 4);
  int*   eidb  = (int*)alloc((size_t)N_EDGES * 4);
  int*   part  = (int*)alloc((size_t)PARTS * 4);

  const int EB = (N_EDGES + 255) / 256;
  const int NB = (N_NODES + 255) / 256;

  // casts
  k_cast_x<<<(M_PAD * IN_CH / 4 + 255) / 256, 256, 0, stream>>>(x, xh);
  k_cast_w1t<<<dim3(IN_CH / 64, HC / 64), 256, 0, stream>>>(W1, w1t);
  // GEMM1 (MFMA fp16)
  k_gemm1_mfma<<<dim3(M_PAD / 128, HC / 128), 256, 0, stream>>>(xh, w1t, h);
  // attention logits layer 1 (+ denom self-seed)
  k_al1<<<N_NODES, 256, 0, stream>>>(h, a_s1, a_d1, al_s1v, al_d1v, den1);
  // CSR build
  k_zero_int<<<NB, 256, 0, stream>>>(cnt, N_NODES);
  k_count<<<EB, 256, 0, stream>>>(dstv, cnt);
  k_scan_part<<<PARTS, 256, 0, stream>>>(cnt, part);
  k_scan_tops<<<1, 128, 0, stream>>>(part, offs);
  k_scan_final<<<PARTS, 256, 0, stream>>>(cnt, part, offs, cursor);
  k_scatter<<<EB, 256, 0, stream>>>(dstv, cursor, eidb);
  // edge softmax numerators + denoms
  k_edge1<<<EB, 256, 0, stream>>>(srcv, dstv, al_s1v, al_d1v, p1, den1);
  // aggregate + bias + ELU
  k_agg1<<<N_NODES, 256, 0, stream>>>(h, p1, den1, al_s1v, al_d1v, offs, eidb, srcv, b1, hm);
  // GEMM2
  k_gemm2<<<(N_NODES + G2_TM - 1) / G2_TM, 256, 0, stream>>>(hm, W2, zpre);
  // layer-2 attention
  k_al2<<<NB, 256, 0, stream>>>(zpre, a_s2, a_d2, al_s2v, al_d2v, den2);
  k_edge2<<<EB, 256, 0, stream>>>(srcv, dstv, al_s2v, al_d2v, p2, den2);
  k_agg2<<<(N_NODES + 3) / 4, 256, 0, stream>>>(zpre, p2, den2, al_s2v, al_d2v, offs, eidb,
                                                srcv, b2, zout);
  // decoder
  k_dec<<<N_NODES / 16, 256, 0, stream>>>(zout, Wd, bd, xhat);
}

// Round 3
// 336.694 us; speedup vs baseline: 1.9826x; 1.4464x over previous
//
#include <hip/hip_runtime.h>
#include <hip/hip_bf16.h>
#include <stdint.h>

#define N_NODES 20000
#define N_EDGES 320000
#define IN_CH 512
#define HID 128
#define HEADS 4
#define HC 512          // HEADS*HID
#define OUT_CH 30
#define NEG_SLOPE 0.2f
#define M_PAD 20096     // 157 * 128

typedef _Float16 half8 __attribute__((ext_vector_type(8)));
typedef _Float16 half4v __attribute__((ext_vector_type(4)));
typedef _Float16 half2v __attribute__((ext_vector_type(2)));
typedef float f32x4 __attribute__((ext_vector_type(4)));

static __device__ __forceinline__ float lrelu(float e) { return e > 0.f ? e : NEG_SLOPE * e; }

// async global->LDS, 16B per lane; dest = wave-uniform base + lane*16
static __device__ __forceinline__ void gload16(const void* gsrc, void* ldst) {
  __builtin_amdgcn_global_load_lds(
      (const __attribute__((address_space(1))) uint32_t*)gsrc,
      (__attribute__((address_space(3))) uint32_t*)ldst,
      16, 0, 0);
}

// ------------------------- cast x -> fp16 (padded rows zeroed) ---------------
__global__ __launch_bounds__(256) void k_cast_x(const float* __restrict__ x,
                                                _Float16* __restrict__ xh) {
  int i = blockIdx.x * blockDim.x + threadIdx.x;
  int base = i * 4;
  int row = base >> 9;
  half4v o;
  if (row < N_NODES) {
    float4 v = *(const float4*)(x + (size_t)base);
    o[0] = (_Float16)v.x; o[1] = (_Float16)v.y; o[2] = (_Float16)v.z; o[3] = (_Float16)v.w;
  } else {
    o[0] = o[1] = o[2] = o[3] = (_Float16)0.f;
  }
  *(half4v*)(xh + (size_t)base) = o;
}

// ------------------- cast + transpose W1 [k][n] -> W1t fp16 [n][k] ----------
__global__ __launch_bounds__(256) void k_cast_w1t(const float* __restrict__ W1,
                                                  _Float16* __restrict__ W1t) {
  __shared__ float t[64][65];
  const int bk = blockIdx.x * 64;
  const int bn = blockIdx.y * 64;
  const int tid = threadIdx.x;
#pragma unroll
  for (int it = 0; it < 16; it++) {
    int idx = tid + it * 256;
    int r = idx >> 6, c = idx & 63;
    t[r][c] = W1[(size_t)(bk + r) * HC + bn + c];
  }
  __syncthreads();
#pragma unroll
  for (int it = 0; it < 16; it++) {
    int idx = tid + it * 256;
    int rn = idx >> 6, ck = idx & 63;
    W1t[(size_t)(bn + rn) * IN_CH + bk + ck] = (_Float16)t[ck][rn];
  }
}

// ---------------- GEMM1 (MFMA fp16): h = x @ W1, output fp16 ----------------
__global__ __launch_bounds__(256) void k_gemm1_mfma(const _Float16* __restrict__ A,
                                                    const _Float16* __restrict__ Bt,
                                                    _Float16* __restrict__ C) {
  __shared__ _Float16 As[128 * 64];
  __shared__ _Float16 Bs[128 * 64];
  const int tid = threadIdx.x;
  const int lane = tid & 63;
  const int w = tid >> 6;
  const int bm = blockIdx.x * 128;
  const int bn = blockIdx.y * 128;

  const int lrow = lane >> 3;
  const int schunk = (lane & 7) ^ lrow;

  const int wm = w >> 1, wn = w & 1;
  const int r15 = lane & 15;
  const int q = lane >> 4;
  const int a_row0 = wm * 64 + r15;
  const int b_row0 = wn * 64 + r15;

  f32x4 acc[4][4];
  const f32x4 zero = {0.f, 0.f, 0.f, 0.f};
#pragma unroll
  for (int i = 0; i < 4; i++)
#pragma unroll
    for (int j = 0; j < 4; j++) acc[i][j] = zero;

  for (int kb = 0; kb < 8; kb++) {
    const int kof = kb * 64 + schunk * 8;
#pragma unroll
    for (int t = 0; t < 4; t++) {
      const int row = w * 32 + t * 8;
      gload16(A + (size_t)(bm + row + lrow) * IN_CH + kof, (void*)(As + row * 64));
      gload16(Bt + (size_t)(bn + row + lrow) * IN_CH + kof, (void*)(Bs + row * 64));
    }
    __syncthreads();
#pragma unroll
    for (int s = 0; s < 2; s++) {
      const int cs = ((s * 4 + q) ^ (lane & 7)) * 8;
      half8 af[4], bf[4];
#pragma unroll
      for (int i = 0; i < 4; i++) af[i] = *(const half8*)&As[(a_row0 + i * 16) * 64 + cs];
#pragma unroll
      for (int j = 0; j < 4; j++) bf[j] = *(const half8*)&Bs[(b_row0 + j * 16) * 64 + cs];
#pragma unroll
      for (int i = 0; i < 4; i++)
#pragma unroll
        for (int j = 0; j < 4; j++)
          acc[i][j] = __builtin_amdgcn_mfma_f32_16x16x32_f16(af[i], bf[j], acc[i][j], 0, 0, 0);
    }
    __syncthreads();
  }
#pragma unroll
  for (int i = 0; i < 4; i++) {
#pragma unroll
    for (int j = 0; j < 4; j++) {
      const int gn = bn + wn * 64 + j * 16 + r15;
#pragma unroll
      for (int r = 0; r < 4; r++) {
        const int gm = bm + wm * 64 + i * 16 + q * 4 + r;
        if (gm < N_NODES) C[(size_t)gm * HC + gn] = (_Float16)acc[i][j][r];
      }
    }
  }
}

// ------------- per-node attention logits layer 1 (fp16 h) -------------------
__global__ __launch_bounds__(256) void k_al1(const _Float16* __restrict__ h,
                                             const float* __restrict__ a_src,
                                             const float* __restrict__ a_dst,
                                             float* __restrict__ al_s,
                                             float* __restrict__ al_d) {
  const int n = blockIdx.x;
  const int head = threadIdx.x >> 6;
  const int lane = threadIdx.x & 63;
  const _Float16* hp = h + (size_t)n * HC + head * HID;
  half2v hv2 = *(const half2v*)(hp + lane * 2);
  float2 av = *(const float2*)(a_src + head * HID + lane * 2);
  float2 dv = *(const float2*)(a_dst + head * HID + lane * 2);
  float hx = (float)hv2[0], hy = (float)hv2[1];
  float s = hx * av.x + hy * av.y;
  float d = hx * dv.x + hy * dv.y;
#pragma unroll
  for (int off = 32; off; off >>= 1) {
    s += __shfl_down(s, off);
    d += __shfl_down(d, off);
  }
  if (lane == 0) {
    al_s[n * HEADS + head] = s;
    al_d[n * HEADS + head] = d;
  }
}

// ------------------------------- CSR build ----------------------------------
#define PARTS 79   // ceil(20000/256)
__global__ void k_zero_int(int* __restrict__ p, int n) {
  int i = blockIdx.x * blockDim.x + threadIdx.x;
  if (i < n) p[i] = 0;
}
__global__ void k_count(const int* __restrict__ dst, int* __restrict__ cnt) {
  int e = blockIdx.x * blockDim.x + threadIdx.x;
  if (e < N_EDGES) atomicAdd(&cnt[dst[e]], 1);
}
__global__ __launch_bounds__(256) void k_scan_part(const int* __restrict__ cnt,
                                                   int* __restrict__ part) {
  __shared__ int ws[4];
  int i = blockIdx.x * 256 + threadIdx.x;
  int v = (i < N_NODES) ? cnt[i] : 0;
  int lane = threadIdx.x & 63;
#pragma unroll
  for (int off = 32; off; off >>= 1) v += __shfl_down(v, off);
  if (lane == 0) ws[threadIdx.x >> 6] = v;
  __syncthreads();
  if (threadIdx.x == 0) part[blockIdx.x] = ws[0] + ws[1] + ws[2] + ws[3];
}
__global__ __launch_bounds__(128) void k_scan_tops(int* __restrict__ part,
                                                   int* __restrict__ offs) {
  __shared__ int buf[128];
  int t = threadIdx.x;
  int v = (t < PARTS) ? part[t] : 0;
  buf[t] = v;
  __syncthreads();
#pragma unroll
  for (int off = 1; off < 128; off <<= 1) {
    int x = (t >= off) ? buf[t - off] : 0;
    __syncthreads();
    buf[t] += x;
    __syncthreads();
  }
  if (t < PARTS) part[t] = buf[t] - v;
  if (t == PARTS - 1) offs[N_NODES] = buf[t];
}
__global__ __launch_bounds__(256) void k_scan_final(const int* __restrict__ cnt,
                                                    const int* __restrict__ part,
                                                    int* __restrict__ offs,
                                                    int* __restrict__ cursor) {
  __shared__ int buf[256];
  int i = blockIdx.x * 256 + threadIdx.x;
  int t = threadIdx.x;
  int v = (i < N_NODES) ? cnt[i] : 0;
  buf[t] = v;
  __syncthreads();
#pragma unroll
  for (int off = 1; off < 256; off <<= 1) {
    int x = (t >= off) ? buf[t - off] : 0;
    __syncthreads();
    buf[t] += x;
    __syncthreads();
  }
  if (i < N_NODES) {
    int ex = part[blockIdx.x] + buf[t] - v;
    offs[i] = ex;
    cursor[i] = ex;
  }
}
__global__ void k_scatter(const int* __restrict__ dst, int* __restrict__ cursor,
                          int* __restrict__ eid) {
  int e = blockIdx.x * blockDim.x + threadIdx.x;
  if (e < N_EDGES) {
    int pos = atomicAdd(&cursor[dst[e]], 1);
    eid[pos] = e;
  }
}

// ---------- aggregation layer 1, fused softmax (unnorm + denom) -------------
__global__ __launch_bounds__(256) void k_agg1(const _Float16* __restrict__ h,
                                              const float* __restrict__ al_s,
                                              const float* __restrict__ al_d,
                                              const int* __restrict__ offs,
                                              const int* __restrict__ eid,
                                              const int* __restrict__ srcv,
                                              const float* __restrict__ b1,
                                              _Float16* __restrict__ hm) {
  const int n = blockIdx.x;
  const int tid = threadIdx.x;
  const int head = tid >> 6;      // wave-uniform
  __shared__ int s_src[64];
  __shared__ float s_p[HEADS][64];
  const float4 asn = *(const float4*)(al_s + (size_t)n * 4);
  const float4 adn = *(const float4*)(al_d + (size_t)n * 4);
  const float as_h = (head == 0) ? asn.x : (head == 1) ? asn.y : (head == 2) ? asn.z : asn.w;
  const float ad_h = (head == 0) ? adn.x : (head == 1) ? adn.y : (head == 2) ? adn.z : adn.w;
  const float pself = __expf(lrelu(as_h + ad_h));

  const int c = tid * 2;
  half2v hv2 = *(const half2v*)(h + (size_t)n * HC + c);
  float accx = pself * (float)hv2[0], accy = pself * (float)hv2[1];
  float den = pself;

  const int beg = offs[n], end = offs[n + 1];
  for (int base = beg; base < end; base += 64) {
    int m = min(64, end - base);
    if (tid < m) {
      int e = eid[base + tid];
      int s = srcv[e];
      s_src[tid] = s;
      float4 as = *(const float4*)(al_s + (size_t)s * 4);
      s_p[0][tid] = __expf(lrelu(as.x + adn.x));
      s_p[1][tid] = __expf(lrelu(as.y + adn.y));
      s_p[2][tid] = __expf(lrelu(as.z + adn.z));
      s_p[3][tid] = __expf(lrelu(as.w + adn.w));
    }
    __syncthreads();
    for (int qq = 0; qq < m; qq++) {
      float p = s_p[head][qq];                 // broadcast
      half2v v2 = *(const half2v*)(h + (size_t)s_src[qq] * HC + c);
      den += p;
      accx += p * (float)v2[0];
      accy += p * (float)v2[1];
    }
    __syncthreads();
  }
  const float inv = 1.f / den;
  float2 bb = *(const float2*)(b1 + c);
  float o0 = accx * inv + bb.x, o1 = accy * inv + bb.y;
  o0 = o0 > 0.f ? o0 : __expf(o0) - 1.f;   // ELU
  o1 = o1 > 0.f ? o1 : __expf(o1) - 1.f;
  half2v ov; ov[0] = (_Float16)o0; ov[1] = (_Float16)o1;
  *(half2v*)(hm + (size_t)n * HC + c) = ov;
}

// ---------------- GEMM2: zpre = hm(fp16) @ W2  [20000,512]x[512,30] ---------
#define G2_TM 64
#define G2_TK 64
__global__ __launch_bounds__(256) void k_gemm2(const _Float16* __restrict__ A,
                                               const float* __restrict__ W2,
                                               float* __restrict__ zpre) {
  __shared__ float As[G2_TM][G2_TK + 4];
  __shared__ float Ws[G2_TK][32];
  const int bm = blockIdx.x * G2_TM;
  const int tid = threadIdx.x;
  const int mg = tid >> 4;
  const int cg = tid & 15;
  const int lr = tid >> 4;
  const int lc = (tid & 15) * 4;
  float acc[4][2] = {};
  for (int kt = 0; kt < HC; kt += G2_TK) {
#pragma unroll
    for (int p = 0; p < 4; p++) {
      int m = p * 16 + lr;
      int gm = bm + m;
      float4 v = make_float4(0.f, 0.f, 0.f, 0.f);
      if (gm < N_NODES) {
        half4v hv = *(const half4v*)(A + (size_t)gm * HC + kt + lc);
        v = make_float4((float)hv[0], (float)hv[1], (float)hv[2], (float)hv[3]);
      }
      *(float4*)&As[m][lc] = v;
    }
    for (int idx = tid; idx < G2_TK * 32; idx += 256) {
      int r = idx >> 5, c = idx & 31;
      Ws[r][c] = (c < OUT_CH) ? W2[(size_t)(kt + r) * OUT_CH + c] : 0.f;
    }
    __syncthreads();
#pragma unroll
    for (int kk = 0; kk < G2_TK; kk++) {
      float b0 = Ws[kk][cg * 2];
      float b1v = Ws[kk][cg * 2 + 1];
#pragma unroll
      for (int i = 0; i < 4; i++) {
        float a = As[mg * 4 + i][kk];
        acc[i][0] += a * b0;
        acc[i][1] += a * b1v;
      }
    }
    __syncthreads();
  }
  const int c = cg * 2;
  if (c < OUT_CH) {
#pragma unroll
    for (int i = 0; i < 4; i++) {
      int gm = bm + mg * 4 + i;
      if (gm < N_NODES)
        *(float2*)(zpre + (size_t)gm * OUT_CH + c) = make_float2(acc[i][0], acc[i][1]);
    }
  }
}

// ------------- layer-2 logits (1 head, C=30) --------------------------------
__global__ void k_al2(const float* __restrict__ zpre, const float* __restrict__ a_s,
                      const float* __restrict__ a_d, float* __restrict__ al_s2,
                      float* __restrict__ al_d2) {
  int n = blockIdx.x * blockDim.x + threadIdx.x;
  if (n >= N_NODES) return;
  const float* z = zpre + (size_t)n * OUT_CH;
  float s = 0.f, d = 0.f;
#pragma unroll
  for (int c = 0; c < OUT_CH; c++) {
    float v = z[c];
    s += v * a_s[c];
    d += v * a_d[c];
  }
  al_s2[n] = s;
  al_d2[n] = d;
}

// ---------- aggregation layer 2, fused softmax -> z (d_out) -----------------
__global__ __launch_bounds__(256) void k_agg2(const float* __restrict__ zpre,
                                              const float* __restrict__ al_s2,
                                              const float* __restrict__ al_d2,
                                              const int* __restrict__ offs,
                                              const int* __restrict__ eid,
                                              const int* __restrict__ srcv,
                                              const float* __restrict__ b2,
                                              float* __restrict__ zout) {
  const int n = blockIdx.x * 4 + (threadIdx.x >> 6);
  const int lane = threadIdx.x & 63;
  if (n >= N_NODES) return;
  const float ad2n = al_d2[n];
  const float pself = __expf(lrelu(al_s2[n] + ad2n));
  float zv = (lane < OUT_CH) ? zpre[(size_t)n * OUT_CH + lane] : 0.f;
  float acc = pself * zv;
  float den = pself;
  const int beg = offs[n], end = offs[n + 1];
  for (int base = beg; base < end; base += 64) {
    int m = min(64, end - base);
    int e = (lane < m) ? eid[base + lane] : 0;
    int ssrc = (lane < m) ? srcv[e] : 0;
    float pp = (lane < m) ? __expf(lrelu(al_s2[ssrc] + ad2n)) : 0.f;
    for (int qq = 0; qq < m; qq++) {
      int s = __shfl(ssrc, qq);
      float p = __shfl(pp, qq);
      den += p;
      float sv = (lane < OUT_CH) ? zpre[(size_t)s * OUT_CH + lane] : 0.f;
      acc += p * sv;
    }
  }
  if (lane < OUT_CH) zout[(size_t)n * OUT_CH + lane] = acc / den + b2[lane];
}

// ---------------- decoder: x_hat = z @ Wd + bd  [20000,30]x[30,512] ---------
__global__ __launch_bounds__(256) void k_dec(const float* __restrict__ z,
                                             const float* __restrict__ Wd,
                                             const float* __restrict__ bd,
                                             float* __restrict__ xhat) {
  __shared__ float zs[16][32];
  const int tid = threadIdx.x;
  const int c = tid * 2;
  // Wd column pair in registers (k padded to 32 with zeros)
  float wd0[32], wd1[32];
#pragma unroll
  for (int k = 0; k < OUT_CH; k++) {
    float2 wv = *(const float2*)(Wd + (size_t)k * IN_CH + c);
    wd0[k] = wv.x; wd1[k] = wv.y;
  }
  wd0[30] = wd0[31] = wd1[30] = wd1[31] = 0.f;
  const int n0 = blockIdx.x * 16;
  for (int idx = tid; idx < 16 * 32; idx += 256) {
    int r = idx >> 5, cc = idx & 31;
    zs[r][cc] = (cc < OUT_CH) ? z[(size_t)(n0 + r) * OUT_CH + cc] : 0.f;
  }
  __syncthreads();
  const float b0 = bd[c], b1v = bd[c + 1];
#pragma unroll 2
  for (int i = 0; i < 16; i++) {
    float a0 = b0, a1 = b1v;
#pragma unroll
    for (int k4 = 0; k4 < 8; k4++) {
      float4 zv = *(const float4*)&zs[i][k4 * 4];   // broadcast b128
      a0 += zv.x * wd0[k4 * 4 + 0] + zv.y * wd0[k4 * 4 + 1] +
            zv.z * wd0[k4 * 4 + 2] + zv.w * wd0[k4 * 4 + 3];
      a1 += zv.x * wd1[k4 * 4 + 0] + zv.y * wd1[k4 * 4 + 1] +
            zv.z * wd1[k4 * 4 + 2] + zv.w * wd1[k4 * 4 + 3];
    }
    *(float2*)(xhat + (size_t)(n0 + i) * IN_CH + c) = make_float2(a0, a1);
  }
}

// ----------------------------------------------------------------------------
extern "C" void kernel_launch(void* const* d_in, const int* in_sizes, int n_in,
                              void* d_out, int out_size, void* d_ws, size_t ws_size,
                              hipStream_t stream) {
  const float* x    = (const float*)d_in[0];
  const int*   ei   = (const int*)d_in[1];
  const float* W1   = (const float*)d_in[2];
  const float* a_s1 = (const float*)d_in[3];
  const float* a_d1 = (const float*)d_in[4];
  const float* b1   = (const float*)d_in[5];
  const float* W2   = (const float*)d_in[6];
  const float* a_s2 = (const float*)d_in[7];
  const float* a_d2 = (const float*)d_in[8];
  const float* b2   = (const float*)d_in[9];
  const float* Wd   = (const float*)d_in[10];
  const float* bd   = (const float*)d_in[11];

  float* xhat = (float*)d_out;
  float* zout = xhat + (size_t)N_NODES * IN_CH;

  const int* srcv = ei;
  const int* dstv = ei + N_EDGES;

  char* w = (char*)d_ws;
  auto alloc = [&](size_t bytes) {
    void* p = (void*)w;
    w += (bytes + 255) & ~(size_t)255;
    return p;
  };
  _Float16* xh   = (_Float16*)alloc((size_t)M_PAD * IN_CH * 2);
  _Float16* w1t  = (_Float16*)alloc((size_t)HC * IN_CH * 2);
  _Float16* h    = (_Float16*)alloc((size_t)N_NODES * HC * 2);
  _Float16* hm   = (_Float16*)alloc((size_t)N_NODES * HC * 2);
  float* zpre  = (float*)alloc((size_t)N_NODES * OUT_CH * 4);
  float* al_s1v= (float*)alloc((size_t)N_NODES * HEADS * 4);
  float* al_d1v= (float*)alloc((size_t)N_NODES * HEADS * 4);
  float* al_s2v= (float*)alloc((size_t)N_NODES * 4);
  float* al_d2v= (float*)alloc((size_t)N_NODES * 4);
  int*   cnt   = (int*)alloc((size_t)N_NODES * 4);
  int*   offs  = (int*)alloc((size_t)(N_NODES + 1) * 4);
  int*   cursor= (int*)alloc((size_t)N_NODES * 4);
  int*   eidb  = (int*)alloc((size_t)N_EDGES * 4);
  int*   part  = (int*)alloc((size_t)PARTS * 4);

  const int EB = (N_EDGES + 255) / 256;
  const int NB = (N_NODES + 255) / 256;

  k_cast_x<<<(M_PAD * IN_CH / 4 + 255) / 256, 256, 0, stream>>>(x, xh);
  k_cast_w1t<<<dim3(IN_CH / 64, HC / 64), 256, 0, stream>>>(W1, w1t);
  k_gemm1_mfma<<<dim3(M_PAD / 128, HC / 128), 256, 0, stream>>>(xh, w1t, h);
  k_al1<<<N_NODES, 256, 0, stream>>>(h, a_s1, a_d1, al_s1v, al_d1v);
  // CSR build
  k_zero_int<<<NB, 256, 0, stream>>>(cnt, N_NODES);
  k_count<<<EB, 256, 0, stream>>>(dstv, cnt);
  k_scan_part<<<PARTS, 256, 0, stream>>>(cnt, part);
  k_scan_tops<<<1, 128, 0, stream>>>(part, offs);
  k_scan_final<<<PARTS, 256, 0, stream>>>(cnt, part, offs, cursor);
  k_scatter<<<EB, 256, 0, stream>>>(dstv, cursor, eidb);
  // fused aggregate layer 1
  k_agg1<<<N_NODES, 256, 0, stream>>>(h, al_s1v, al_d1v, offs, eidb, srcv, b1, hm);
  // GEMM2
  k_gemm2<<<(N_NODES + G2_TM - 1) / G2_TM, 256, 0, stream>>>(hm, W2, zpre);
  // layer-2 attention (fused)
  k_al2<<<NB, 256, 0, stream>>>(zpre, a_s2, a_d2, al_s2v, al_d2v);
  k_agg2<<<(N_NODES + 3) / 4, 256, 0, stream>>>(zpre, al_s2v, al_d2v, offs, eidb, srcv, b2, zout);
  // decoder
  k_dec<<<N_NODES / 16, 256, 0, stream>>>(zout, Wd, bd, xhat);
}

// Round 4
// 329.892 us; speedup vs baseline: 2.0234x; 1.0206x over previous
//
#include <hip/hip_runtime.h>
#include <hip/hip_bf16.h>
#include <stdint.h>

#define N_NODES 20000
#define N_EDGES 320000
#define IN_CH 512
#define HID 128
#define HEADS 4
#define HC 512          // HEADS*HID
#define OUT_CH 30
#define NEG_SLOPE 0.2f
#define M_PAD 20096     // 157 * 128

typedef _Float16 half8 __attribute__((ext_vector_type(8)));
typedef _Float16 half4v __attribute__((ext_vector_type(4)));
typedef _Float16 half2v __attribute__((ext_vector_type(2)));
typedef float f32x4 __attribute__((ext_vector_type(4)));

static __device__ __forceinline__ float lrelu(float e) { return e > 0.f ? e : NEG_SLOPE * e; }

// async global->LDS, 16B per lane; dest = wave-uniform base + lane*16
static __device__ __forceinline__ void gload16(const void* gsrc, void* ldst) {
  __builtin_amdgcn_global_load_lds(
      (const __attribute__((address_space(1))) uint32_t*)gsrc,
      (__attribute__((address_space(3))) uint32_t*)ldst,
      16, 0, 0);
}

// ------------------------- cast x -> fp16 (padded rows zeroed) ---------------
__global__ __launch_bounds__(256) void k_cast_x(const float* __restrict__ x,
                                                _Float16* __restrict__ xh) {
  int i = blockIdx.x * blockDim.x + threadIdx.x;
  int base = i * 4;
  int row = base >> 9;
  half4v o;
  if (row < N_NODES) {
    float4 v = *(const float4*)(x + (size_t)base);
    o[0] = (_Float16)v.x; o[1] = (_Float16)v.y; o[2] = (_Float16)v.z; o[3] = (_Float16)v.w;
  } else {
    o[0] = o[1] = o[2] = o[3] = (_Float16)0.f;
  }
  *(half4v*)(xh + (size_t)base) = o;
}

// ------------------- cast + transpose W1 [k][n] -> W1t fp16 [n][k] ----------
__global__ __launch_bounds__(256) void k_cast_w1t(const float* __restrict__ W1,
                                                  _Float16* __restrict__ W1t) {
  __shared__ float t[64][65];
  const int bk = blockIdx.x * 64;
  const int bn = blockIdx.y * 64;
  const int tid = threadIdx.x;
#pragma unroll
  for (int it = 0; it < 16; it++) {
    int idx = tid + it * 256;
    int r = idx >> 6, c = idx & 63;
    t[r][c] = W1[(size_t)(bk + r) * HC + bn + c];
  }
  __syncthreads();
#pragma unroll
  for (int it = 0; it < 16; it++) {
    int idx = tid + it * 256;
    int rn = idx >> 6, ck = idx & 63;
    W1t[(size_t)(bn + rn) * IN_CH + bk + ck] = (_Float16)t[ck][rn];
  }
}

// ---------------- GEMM1 (MFMA fp16): h = x @ W1, output fp16 ----------------
__global__ __launch_bounds__(256) void k_gemm1_mfma(const _Float16* __restrict__ A,
                                                    const _Float16* __restrict__ Bt,
                                                    _Float16* __restrict__ C) {
  __shared__ _Float16 As[128 * 64];
  __shared__ _Float16 Bs[128 * 64];
  const int tid = threadIdx.x;
  const int lane = tid & 63;
  const int w = tid >> 6;
  const int bm = blockIdx.x * 128;
  const int bn = blockIdx.y * 128;

  const int lrow = lane >> 3;
  const int schunk = (lane & 7) ^ lrow;

  const int wm = w >> 1, wn = w & 1;
  const int r15 = lane & 15;
  const int q = lane >> 4;
  const int a_row0 = wm * 64 + r15;
  const int b_row0 = wn * 64 + r15;

  f32x4 acc[4][4];
  const f32x4 zero = {0.f, 0.f, 0.f, 0.f};
#pragma unroll
  for (int i = 0; i < 4; i++)
#pragma unroll
    for (int j = 0; j < 4; j++) acc[i][j] = zero;

  for (int kb = 0; kb < 8; kb++) {
    const int kof = kb * 64 + schunk * 8;
#pragma unroll
    for (int t = 0; t < 4; t++) {
      const int row = w * 32 + t * 8;
      gload16(A + (size_t)(bm + row + lrow) * IN_CH + kof, (void*)(As + row * 64));
      gload16(Bt + (size_t)(bn + row + lrow) * IN_CH + kof, (void*)(Bs + row * 64));
    }
    __syncthreads();
#pragma unroll
    for (int s = 0; s < 2; s++) {
      const int cs = ((s * 4 + q) ^ (lane & 7)) * 8;
      half8 af[4], bf[4];
#pragma unroll
      for (int i = 0; i < 4; i++) af[i] = *(const half8*)&As[(a_row0 + i * 16) * 64 + cs];
#pragma unroll
      for (int j = 0; j < 4; j++) bf[j] = *(const half8*)&Bs[(b_row0 + j * 16) * 64 + cs];
#pragma unroll
      for (int i = 0; i < 4; i++)
#pragma unroll
        for (int j = 0; j < 4; j++)
          acc[i][j] = __builtin_amdgcn_mfma_f32_16x16x32_f16(af[i], bf[j], acc[i][j], 0, 0, 0);
    }
    __syncthreads();
  }
#pragma unroll
  for (int i = 0; i < 4; i++) {
#pragma unroll
    for (int j = 0; j < 4; j++) {
      const int gn = bn + wn * 64 + j * 16 + r15;
#pragma unroll
      for (int r = 0; r < 4; r++) {
        const int gm = bm + wm * 64 + i * 16 + q * 4 + r;
        if (gm < N_NODES) C[(size_t)gm * HC + gn] = (_Float16)acc[i][j][r];
      }
    }
  }
}

// ------- per-node attention logits layer 1: grid-stride waves, regs for a ---
__global__ __launch_bounds__(256) void k_al1(const _Float16* __restrict__ h,
                                             const float* __restrict__ a_src,
                                             const float* __restrict__ a_dst,
                                             float* __restrict__ al_s,
                                             float* __restrict__ al_d) {
  const int lane = threadIdx.x & 63;
  const int wid = (blockIdx.x * 256 + threadIdx.x) >> 6;   // 0..1023
  const int c0 = lane * 8;
  float as[8], ad[8];
#pragma unroll
  for (int j = 0; j < 8; j++) {
    as[j] = a_src[c0 + j];
    ad[j] = a_dst[c0 + j];
  }
  for (int n = wid; n < N_NODES; n += 1024) {
    half8 hv = *(const half8*)(h + (size_t)n * HC + c0);
    float s = 0.f, d = 0.f;
#pragma unroll
    for (int j = 0; j < 8; j++) {
      float hf = (float)hv[j];
      s += hf * as[j];
      d += hf * ad[j];
    }
#pragma unroll
    for (int off = 8; off; off >>= 1) {
      s += __shfl_down(s, off);
      d += __shfl_down(d, off);
    }
    if ((lane & 15) == 0) {
      al_s[n * HEADS + (lane >> 4)] = s;
      al_d[n * HEADS + (lane >> 4)] = d;
    }
  }
}

// ------------------------------- CSR build ----------------------------------
#define PARTS 79   // ceil(20000/256)
__global__ void k_zero_int(int* __restrict__ p, int n) {
  int i = blockIdx.x * blockDim.x + threadIdx.x;
  if (i < n) p[i] = 0;
}
__global__ void k_count(const int* __restrict__ dst, int* __restrict__ cnt) {
  int e = blockIdx.x * blockDim.x + threadIdx.x;
  if (e < N_EDGES) atomicAdd(&cnt[dst[e]], 1);
}
__global__ __launch_bounds__(256) void k_scan_part(const int* __restrict__ cnt,
                                                   int* __restrict__ part) {
  __shared__ int ws[4];
  int i = blockIdx.x * 256 + threadIdx.x;
  int v = (i < N_NODES) ? cnt[i] : 0;
  int lane = threadIdx.x & 63;
#pragma unroll
  for (int off = 32; off; off >>= 1) v += __shfl_down(v, off);
  if (lane == 0) ws[threadIdx.x >> 6] = v;
  __syncthreads();
  if (threadIdx.x == 0) part[blockIdx.x] = ws[0] + ws[1] + ws[2] + ws[3];
}
__global__ __launch_bounds__(128) void k_scan_tops(int* __restrict__ part,
                                                   int* __restrict__ offs) {
  __shared__ int buf[128];
  int t = threadIdx.x;
  int v = (t < PARTS) ? part[t] : 0;
  buf[t] = v;
  __syncthreads();
#pragma unroll
  for (int off = 1; off < 128; off <<= 1) {
    int x = (t >= off) ? buf[t - off] : 0;
    __syncthreads();
    buf[t] += x;
    __syncthreads();
  }
  if (t < PARTS) part[t] = buf[t] - v;
  if (t == PARTS - 1) offs[N_NODES] = buf[t];
}
__global__ __launch_bounds__(256) void k_scan_final(const int* __restrict__ cnt,
                                                    const int* __restrict__ part,
                                                    int* __restrict__ offs,
                                                    int* __restrict__ cursor) {
  __shared__ int buf[256];
  int i = blockIdx.x * 256 + threadIdx.x;
  int t = threadIdx.x;
  int v = (i < N_NODES) ? cnt[i] : 0;
  buf[t] = v;
  __syncthreads();
#pragma unroll
  for (int off = 1; off < 256; off <<= 1) {
    int x = (t >= off) ? buf[t - off] : 0;
    __syncthreads();
    buf[t] += x;
    __syncthreads();
  }
  if (i < N_NODES) {
    int ex = part[blockIdx.x] + buf[t] - v;
    offs[i] = ex;
    cursor[i] = ex;
  }
}
__global__ void k_scatter(const int* __restrict__ dst, int* __restrict__ cursor,
                          int* __restrict__ eid) {
  int e = blockIdx.x * blockDim.x + threadIdx.x;
  if (e < N_EDGES) {
    int pos = atomicAdd(&cursor[dst[e]], 1);
    eid[pos] = e;
  }
}

// ---- aggregation layer 1: one wave per node, 16B/lane, barrier-free --------
__global__ __launch_bounds__(256) void k_agg1(const _Float16* __restrict__ h,
                                              const float* __restrict__ al_s,
                                              const float* __restrict__ al_d,
                                              const int* __restrict__ offs,
                                              const int* __restrict__ eid,
                                              const int* __restrict__ srcv,
                                              const float* __restrict__ b1,
                                              _Float16* __restrict__ hm) {
  __shared__ int s_src[4][64];
  __shared__ float s_p[4][64][4];   // [wave][edge][head]
  const int wv = threadIdx.x >> 6;
  const int lane = threadIdx.x & 63;
  const int n = blockIdx.x * 4 + wv;       // grid = 5000 blocks exactly
  const int head = lane >> 4;
  const int c0 = lane * 8;

  const float4 asn = *(const float4*)(al_s + (size_t)n * 4);
  const float4 adn = *(const float4*)(al_d + (size_t)n * 4);
  float4 ps4;
  ps4.x = __expf(lrelu(asn.x + adn.x));
  ps4.y = __expf(lrelu(asn.y + adn.y));
  ps4.z = __expf(lrelu(asn.z + adn.z));
  ps4.w = __expf(lrelu(asn.w + adn.w));
  const float pself = (head == 0) ? ps4.x : (head == 1) ? ps4.y : (head == 2) ? ps4.z : ps4.w;

  const _Float16* hbase = h + c0;
  half8 hv = *(const half8*)(h + (size_t)n * HC + c0);
  float acc[8];
  float den = pself;
#pragma unroll
  for (int j = 0; j < 8; j++) acc[j] = pself * (float)hv[j];

  const int beg = offs[n], end = offs[n + 1];
  for (int base = beg; base < end; base += 64) {
    const int m = min(64, end - base);
    if (lane < m) {
      int e = eid[base + lane];
      int s = srcv[e];
      s_src[wv][lane] = s;
      float4 a4 = *(const float4*)(al_s + (size_t)s * 4);
      float4 p;
      p.x = __expf(lrelu(a4.x + adn.x));
      p.y = __expf(lrelu(a4.y + adn.y));
      p.z = __expf(lrelu(a4.z + adn.z));
      p.w = __expf(lrelu(a4.w + adn.w));
      *(float4*)&s_p[wv][lane][0] = p;
    }
    __builtin_amdgcn_wave_barrier();
    for (int qq = 0; qq < m; qq++) {
      int s = s_src[wv][qq];                    // uniform LDS broadcast
      float p = s_p[wv][qq][head];
      half8 v = *(const half8*)(hbase + (size_t)s * HC);
      den += p;
#pragma unroll
      for (int j = 0; j < 8; j++) acc[j] += p * (float)v[j];
    }
    __builtin_amdgcn_wave_barrier();
  }
  const float inv = 1.f / den;
  float4 bb0 = *(const float4*)(b1 + c0);
  float4 bb1 = *(const float4*)(b1 + c0 + 4);
  float ob[8] = {bb0.x, bb0.y, bb0.z, bb0.w, bb1.x, bb1.y, bb1.z, bb1.w};
  half8 ov;
#pragma unroll
  for (int j = 0; j < 8; j++) {
    float o = acc[j] * inv + ob[j];
    o = o > 0.f ? o : __expf(o) - 1.f;          // ELU
    ov[j] = (_Float16)o;
  }
  *(half8*)(hm + (size_t)n * HC + c0) = ov;
}

// ---------------- GEMM2: zpre = hm(fp16) @ W2  [20000,512]x[512,30] ---------
#define G2_TM 64
#define G2_TK 64
__global__ __launch_bounds__(256) void k_gemm2(const _Float16* __restrict__ A,
                                               const float* __restrict__ W2,
                                               float* __restrict__ zpre) {
  __shared__ float As[G2_TM][G2_TK + 4];
  __shared__ float Ws[G2_TK][32];
  const int bm = blockIdx.x * G2_TM;
  const int tid = threadIdx.x;
  const int mg = tid >> 4;
  const int cg = tid & 15;
  const int lr = tid >> 4;
  const int lc = (tid & 15) * 4;
  float acc[4][2] = {};
  for (int kt = 0; kt < HC; kt += G2_TK) {
#pragma unroll
    for (int p = 0; p < 4; p++) {
      int m = p * 16 + lr;
      int gm = bm + m;
      float4 v = make_float4(0.f, 0.f, 0.f, 0.f);
      if (gm < N_NODES) {
        half4v hv = *(const half4v*)(A + (size_t)gm * HC + kt + lc);
        v = make_float4((float)hv[0], (float)hv[1], (float)hv[2], (float)hv[3]);
      }
      *(float4*)&As[m][lc] = v;
    }
    for (int idx = tid; idx < G2_TK * 32; idx += 256) {
      int r = idx >> 5, c = idx & 31;
      Ws[r][c] = (c < OUT_CH) ? W2[(size_t)(kt + r) * OUT_CH + c] : 0.f;
    }
    __syncthreads();
#pragma unroll
    for (int kk = 0; kk < G2_TK; kk++) {
      float b0 = Ws[kk][cg * 2];
      float b1v = Ws[kk][cg * 2 + 1];
#pragma unroll
      for (int i = 0; i < 4; i++) {
        float a = As[mg * 4 + i][kk];
        acc[i][0] += a * b0;
        acc[i][1] += a * b1v;
      }
    }
    __syncthreads();
  }
  const int c = cg * 2;
  if (c < OUT_CH) {
#pragma unroll
    for (int i = 0; i < 4; i++) {
      int gm = bm + mg * 4 + i;
      if (gm < N_NODES)
        *(float2*)(zpre + (size_t)gm * OUT_CH + c) = make_float2(acc[i][0], acc[i][1]);
    }
  }
}

// ------------- layer-2 logits (1 head, C=30) --------------------------------
__global__ void k_al2(const float* __restrict__ zpre, const float* __restrict__ a_s,
                      const float* __restrict__ a_d, float* __restrict__ al_s2,
                      float* __restrict__ al_d2) {
  int n = blockIdx.x * blockDim.x + threadIdx.x;
  if (n >= N_NODES) return;
  const float* z = zpre + (size_t)n * OUT_CH;
  float s = 0.f, d = 0.f;
#pragma unroll
  for (int c = 0; c < OUT_CH; c++) {
    float v = z[c];
    s += v * a_s[c];
    d += v * a_d[c];
  }
  al_s2[n] = s;
  al_d2[n] = d;
}

// ---------- aggregation layer 2, fused softmax -> z (d_out) -----------------
__global__ __launch_bounds__(256) void k_agg2(const float* __restrict__ zpre,
                                              const float* __restrict__ al_s2,
                                              const float* __restrict__ al_d2,
                                              const int* __restrict__ offs,
                                              const int* __restrict__ eid,
                                              const int* __restrict__ srcv,
                                              const float* __restrict__ b2,
                                              float* __restrict__ zout) {
  const int n = blockIdx.x * 4 + (threadIdx.x >> 6);
  const int lane = threadIdx.x & 63;
  if (n >= N_NODES) return;
  const float ad2n = al_d2[n];
  const float pself = __expf(lrelu(al_s2[n] + ad2n));
  float zv = (lane < OUT_CH) ? zpre[(size_t)n * OUT_CH + lane] : 0.f;
  float acc = pself * zv;
  float den = pself;
  const int beg = offs[n], end = offs[n + 1];
  for (int base = beg; base < end; base += 64) {
    int m = min(64, end - base);
    int e = (lane < m) ? eid[base + lane] : 0;
    int ssrc = (lane < m) ? srcv[e] : 0;
    float pp = (lane < m) ? __expf(lrelu(al_s2[ssrc] + ad2n)) : 0.f;
    for (int qq = 0; qq < m; qq++) {
      int s = __shfl(ssrc, qq);
      float p = __shfl(pp, qq);
      den += p;
      float sv = (lane < OUT_CH) ? zpre[(size_t)s * OUT_CH + lane] : 0.f;
      acc += p * sv;
    }
  }
  if (lane < OUT_CH) zout[(size_t)n * OUT_CH + lane] = acc / den + b2[lane];
}

// ---------------- decoder: x_hat = z @ Wd + bd, 64 rows/block ---------------
__global__ __launch_bounds__(256) void k_dec(const float* __restrict__ z,
                                             const float* __restrict__ Wd,
                                             const float* __restrict__ bd,
                                             float* __restrict__ xhat) {
  __shared__ float zs[64][32];
  const int tid = threadIdx.x;
  const int c = tid * 2;
  float wd0[32], wd1[32];
#pragma unroll
  for (int k = 0; k < OUT_CH; k++) {
    float2 wv = *(const float2*)(Wd + (size_t)k * IN_CH + c);
    wd0[k] = wv.x; wd1[k] = wv.y;
  }
  wd0[30] = wd0[31] = wd1[30] = wd1[31] = 0.f;
  const int n0 = blockIdx.x * 64;
  for (int idx = tid; idx < 64 * 32; idx += 256) {
    int r = idx >> 5, cc = idx & 31;
    int row = n0 + r;
    zs[r][cc] = (cc < OUT_CH && row < N_NODES) ? z[(size_t)row * OUT_CH + cc] : 0.f;
  }
  __syncthreads();
  const float b0 = bd[c], b1v = bd[c + 1];
  for (int i = 0; i < 64; i++) {
    int row = n0 + i;
    if (row >= N_NODES) break;
    float a0 = b0, a1 = b1v;
#pragma unroll
    for (int k4 = 0; k4 < 8; k4++) {
      float4 zv = *(const float4*)&zs[i][k4 * 4];   // broadcast b128
      a0 += zv.x * wd0[k4 * 4 + 0] + zv.y * wd0[k4 * 4 + 1] +
            zv.z * wd0[k4 * 4 + 2] + zv.w * wd0[k4 * 4 + 3];
      a1 += zv.x * wd1[k4 * 4 + 0] + zv.y * wd1[k4 * 4 + 1] +
            zv.z * wd1[k4 * 4 + 2] + zv.w * wd1[k4 * 4 + 3];
    }
    *(float2*)(xhat + (size_t)row * IN_CH + c) = make_float2(a0, a1);
  }
}

// ----------------------------------------------------------------------------
extern "C" void kernel_launch(void* const* d_in, const int* in_sizes, int n_in,
                              void* d_out, int out_size, void* d_ws, size_t ws_size,
                              hipStream_t stream) {
  const float* x    = (const float*)d_in[0];
  const int*   ei   = (const int*)d_in[1];
  const float* W1   = (const float*)d_in[2];
  const float* a_s1 = (const float*)d_in[3];
  const float* a_d1 = (const float*)d_in[4];
  const float* b1   = (const float*)d_in[5];
  const float* W2   = (const float*)d_in[6];
  const float* a_s2 = (const float*)d_in[7];
  const float* a_d2 = (const float*)d_in[8];
  const float* b2   = (const float*)d_in[9];
  const float* Wd   = (const float*)d_in[10];
  const float* bd   = (const float*)d_in[11];

  float* xhat = (float*)d_out;
  float* zout = xhat + (size_t)N_NODES * IN_CH;

  const int* srcv = ei;
  const int* dstv = ei + N_EDGES;

  char* w = (char*)d_ws;
  auto alloc = [&](size_t bytes) {
    void* p = (void*)w;
    w += (bytes + 255) & ~(size_t)255;
    return p;
  };
  _Float16* xh   = (_Float16*)alloc((size_t)M_PAD * IN_CH * 2);
  _Float16* w1t  = (_Float16*)alloc((size_t)HC * IN_CH * 2);
  _Float16* h    = (_Float16*)alloc((size_t)N_NODES * HC * 2);
  _Float16* hm   = (_Float16*)alloc((size_t)N_NODES * HC * 2);
  float* zpre  = (float*)alloc((size_t)N_NODES * OUT_CH * 4);
  float* al_s1v= (float*)alloc((size_t)N_NODES * HEADS * 4);
  float* al_d1v= (float*)alloc((size_t)N_NODES * HEADS * 4);
  float* al_s2v= (float*)alloc((size_t)N_NODES * 4);
  float* al_d2v= (float*)alloc((size_t)N_NODES * 4);
  int*   cnt   = (int*)alloc((size_t)N_NODES * 4);
  int*   offs  = (int*)alloc((size_t)(N_NODES + 1) * 4);
  int*   cursor= (int*)alloc((size_t)N_NODES * 4);
  int*   eidb  = (int*)alloc((size_t)N_EDGES * 4);
  int*   part  = (int*)alloc((size_t)PARTS * 4);

  const int EB = (N_EDGES + 255) / 256;
  const int NB = (N_NODES + 255) / 256;

  k_cast_x<<<(M_PAD * IN_CH / 4 + 255) / 256, 256, 0, stream>>>(x, xh);
  k_cast_w1t<<<dim3(IN_CH / 64, HC / 64), 256, 0, stream>>>(W1, w1t);
  k_gemm1_mfma<<<dim3(M_PAD / 128, HC / 128), 256, 0, stream>>>(xh, w1t, h);
  k_al1<<<256, 256, 0, stream>>>(h, a_s1, a_d1, al_s1v, al_d1v);
  // CSR build
  k_zero_int<<<NB, 256, 0, stream>>>(cnt, N_NODES);
  k_count<<<EB, 256, 0, stream>>>(dstv, cnt);
  k_scan_part<<<PARTS, 256, 0, stream>>>(cnt, part);
  k_scan_tops<<<1, 128, 0, stream>>>(part, offs);
  k_scan_final<<<PARTS, 256, 0, stream>>>(cnt, part, offs, cursor);
  k_scatter<<<EB, 256, 0, stream>>>(dstv, cursor, eidb);
  // fused aggregate layer 1 (wave per node)
  k_agg1<<<N_NODES / 4, 256, 0, stream>>>(h, al_s1v, al_d1v, offs, eidb, srcv, b1, hm);
  // GEMM2
  k_gemm2<<<(N_NODES + G2_TM - 1) / G2_TM, 256, 0, stream>>>(hm, W2, zpre);
  // layer-2 attention (fused)
  k_al2<<<NB, 256, 0, stream>>>(zpre, a_s2, a_d2, al_s2v, al_d2v);
  k_agg2<<<(N_NODES + 3) / 4, 256, 0, stream>>>(zpre, al_s2v, al_d2v, offs, eidb, srcv, b2, zout);
  // decoder
  k_dec<<<(N_NODES + 63) / 64, 256, 0, stream>>>(zout, Wd, bd, xhat);
}

// Round 5
// 300.908 us; speedup vs baseline: 2.2183x; 1.0963x over previous
//
#include <hip/hip_runtime.h>
#include <hip/hip_bf16.h>
#include <stdint.h>

#define N_NODES 20000
#define N_EDGES 320000
#define IN_CH 512
#define HID 128
#define HEADS 4
#define HC 512          // HEADS*HID
#define OUT_CH 30
#define NEG_SLOPE 0.2f
#define M_PAD 20096     // 157 * 128

typedef _Float16 half8 __attribute__((ext_vector_type(8)));
typedef _Float16 half4v __attribute__((ext_vector_type(4)));
typedef _Float16 half2v __attribute__((ext_vector_type(2)));
typedef float f32x4 __attribute__((ext_vector_type(4)));

static __device__ __forceinline__ float lrelu(float e) { return e > 0.f ? e : NEG_SLOPE * e; }

// async global->LDS, 16B per lane; dest = wave-uniform base + lane*16
static __device__ __forceinline__ void gload16(const void* gsrc, void* ldst) {
  __builtin_amdgcn_global_load_lds(
      (const __attribute__((address_space(1))) uint32_t*)gsrc,
      (__attribute__((address_space(3))) uint32_t*)ldst,
      16, 0, 0);
}

// ------------------------- cast x -> fp16 (padded rows zeroed) ---------------
__global__ __launch_bounds__(256) void k_cast_x(const float* __restrict__ x,
                                                _Float16* __restrict__ xh) {
  int i = blockIdx.x * blockDim.x + threadIdx.x;
  int base = i * 4;
  int row = base >> 9;
  half4v o;
  if (row < N_NODES) {
    float4 v = *(const float4*)(x + (size_t)base);
    o[0] = (_Float16)v.x; o[1] = (_Float16)v.y; o[2] = (_Float16)v.z; o[3] = (_Float16)v.w;
  } else {
    o[0] = o[1] = o[2] = o[3] = (_Float16)0.f;
  }
  *(half4v*)(xh + (size_t)base) = o;
}

// ------------------- cast + transpose W1 [k][n] -> W1t fp16 [n][k] ----------
__global__ __launch_bounds__(256) void k_cast_w1t(const float* __restrict__ W1,
                                                  _Float16* __restrict__ W1t) {
  __shared__ float t[64][65];
  const int bk = blockIdx.x * 64;
  const int bn = blockIdx.y * 64;
  const int tid = threadIdx.x;
#pragma unroll
  for (int it = 0; it < 16; it++) {
    int idx = tid + it * 256;
    int r = idx >> 6, c = idx & 63;
    t[r][c] = W1[(size_t)(bk + r) * HC + bn + c];
  }
  __syncthreads();
#pragma unroll
  for (int it = 0; it < 16; it++) {
    int idx = tid + it * 256;
    int rn = idx >> 6, ck = idx & 63;
    W1t[(size_t)(bn + rn) * IN_CH + bk + ck] = (_Float16)t[ck][rn];
  }
}

// ---------- cast W2 [512][30] fp32 -> w2t fp16 [32][512] (n-major, padded) --
__global__ __launch_bounds__(256) void k_cast_w2t(const float* __restrict__ W2,
                                                  _Float16* __restrict__ w2t) {
  int idx = blockIdx.x * blockDim.x + threadIdx.x;   // over 32*512
  if (idx >= 32 * 512) return;
  int n = idx >> 9, k = idx & 511;
  w2t[idx] = (n < OUT_CH) ? (_Float16)W2[(size_t)k * OUT_CH + n] : (_Float16)0.f;
}

// ---------------- GEMM1 (MFMA fp16): h = x @ W1, output fp16 ----------------
__global__ __launch_bounds__(256) void k_gemm1_mfma(const _Float16* __restrict__ A,
                                                    const _Float16* __restrict__ Bt,
                                                    _Float16* __restrict__ C) {
  __shared__ _Float16 As[128 * 64];
  __shared__ _Float16 Bs[128 * 64];
  const int tid = threadIdx.x;
  const int lane = tid & 63;
  const int w = tid >> 6;
  const int bm = blockIdx.x * 128;
  const int bn = blockIdx.y * 128;

  const int lrow = lane >> 3;
  const int schunk = (lane & 7) ^ lrow;

  const int wm = w >> 1, wn = w & 1;
  const int r15 = lane & 15;
  const int q = lane >> 4;
  const int a_row0 = wm * 64 + r15;
  const int b_row0 = wn * 64 + r15;

  f32x4 acc[4][4];
  const f32x4 zero = {0.f, 0.f, 0.f, 0.f};
#pragma unroll
  for (int i = 0; i < 4; i++)
#pragma unroll
    for (int j = 0; j < 4; j++) acc[i][j] = zero;

  for (int kb = 0; kb < 8; kb++) {
    const int kof = kb * 64 + schunk * 8;
#pragma unroll
    for (int t = 0; t < 4; t++) {
      const int row = w * 32 + t * 8;
      gload16(A + (size_t)(bm + row + lrow) * IN_CH + kof, (void*)(As + row * 64));
      gload16(Bt + (size_t)(bn + row + lrow) * IN_CH + kof, (void*)(Bs + row * 64));
    }
    __syncthreads();
#pragma unroll
    for (int s = 0; s < 2; s++) {
      const int cs = ((s * 4 + q) ^ (lane & 7)) * 8;
      half8 af[4], bf[4];
#pragma unroll
      for (int i = 0; i < 4; i++) af[i] = *(const half8*)&As[(a_row0 + i * 16) * 64 + cs];
#pragma unroll
      for (int j = 0; j < 4; j++) bf[j] = *(const half8*)&Bs[(b_row0 + j * 16) * 64 + cs];
#pragma unroll
      for (int i = 0; i < 4; i++)
#pragma unroll
        for (int j = 0; j < 4; j++)
          acc[i][j] = __builtin_amdgcn_mfma_f32_16x16x32_f16(af[i], bf[j], acc[i][j], 0, 0, 0);
    }
    __syncthreads();
  }
#pragma unroll
  for (int i = 0; i < 4; i++) {
#pragma unroll
    for (int j = 0; j < 4; j++) {
      const int gn = bn + wn * 64 + j * 16 + r15;
#pragma unroll
      for (int r = 0; r < 4; r++) {
        const int gm = bm + wm * 64 + i * 16 + q * 4 + r;
        if (gm < N_NODES) C[(size_t)gm * HC + gn] = (_Float16)acc[i][j][r];
      }
    }
  }
}

// ------- per-node attention logits layer 1: grid-stride waves, regs for a ---
__global__ __launch_bounds__(256) void k_al1(const _Float16* __restrict__ h,
                                             const float* __restrict__ a_src,
                                             const float* __restrict__ a_dst,
                                             float* __restrict__ al_s,
                                             float* __restrict__ al_d) {
  const int lane = threadIdx.x & 63;
  const int wid = (blockIdx.x * 256 + threadIdx.x) >> 6;   // 0..1023
  const int c0 = lane * 8;
  float as[8], ad[8];
#pragma unroll
  for (int j = 0; j < 8; j++) {
    as[j] = a_src[c0 + j];
    ad[j] = a_dst[c0 + j];
  }
  for (int n = wid; n < N_NODES; n += 1024) {
    half8 hv = *(const half8*)(h + (size_t)n * HC + c0);
    float s = 0.f, d = 0.f;
#pragma unroll
    for (int j = 0; j < 8; j++) {
      float hf = (float)hv[j];
      s += hf * as[j];
      d += hf * ad[j];
    }
#pragma unroll
    for (int off = 8; off; off >>= 1) {
      s += __shfl_down(s, off);
      d += __shfl_down(d, off);
    }
    if ((lane & 15) == 0) {
      al_s[n * HEADS + (lane >> 4)] = s;
      al_d[n * HEADS + (lane >> 4)] = d;
    }
  }
}

// ------------------------------- CSR build ----------------------------------
#define PARTS 79   // ceil(20000/256)
__global__ void k_count(const int* __restrict__ dst, int* __restrict__ cnt) {
  int e = blockIdx.x * blockDim.x + threadIdx.x;
  if (e < N_EDGES) atomicAdd(&cnt[dst[e]], 1);
}
__global__ __launch_bounds__(256) void k_scan_part(const int* __restrict__ cnt,
                                                   int* __restrict__ part) {
  __shared__ int ws[4];
  int i = blockIdx.x * 256 + threadIdx.x;
  int v = (i < N_NODES) ? cnt[i] : 0;
  int lane = threadIdx.x & 63;
#pragma unroll
  for (int off = 32; off; off >>= 1) v += __shfl_down(v, off);
  if (lane == 0) ws[threadIdx.x >> 6] = v;
  __syncthreads();
  if (threadIdx.x == 0) part[blockIdx.x] = ws[0] + ws[1] + ws[2] + ws[3];
}
__global__ __launch_bounds__(128) void k_scan_tops(int* __restrict__ part,
                                                   int* __restrict__ offs) {
  __shared__ int buf[128];
  int t = threadIdx.x;
  int v = (t < PARTS) ? part[t] : 0;
  buf[t] = v;
  __syncthreads();
#pragma unroll
  for (int off = 1; off < 128; off <<= 1) {
    int x = (t >= off) ? buf[t - off] : 0;
    __syncthreads();
    buf[t] += x;
    __syncthreads();
  }
  if (t < PARTS) part[t] = buf[t] - v;
  if (t == PARTS - 1) offs[N_NODES] = buf[t];
}
__global__ __launch_bounds__(256) void k_scan_final(const int* __restrict__ cnt,
                                                    const int* __restrict__ part,
                                                    int* __restrict__ offs,
                                                    int* __restrict__ cursor) {
  __shared__ int buf[256];
  int i = blockIdx.x * 256 + threadIdx.x;
  int t = threadIdx.x;
  int v = (i < N_NODES) ? cnt[i] : 0;
  buf[t] = v;
  __syncthreads();
#pragma unroll
  for (int off = 1; off < 256; off <<= 1) {
    int x = (t >= off) ? buf[t - off] : 0;
    __syncthreads();
    buf[t] += x;
    __syncthreads();
  }
  if (i < N_NODES) {
    int ex = part[blockIdx.x] + buf[t] - v;
    offs[i] = ex;
    cursor[i] = ex;
  }
}
// scatter SOURCE ids directly (kills the eid->srcv double-gather downstream)
__global__ void k_scatter(const int* __restrict__ src, const int* __restrict__ dst,
                          int* __restrict__ cursor, int* __restrict__ srcs) {
  int e = blockIdx.x * blockDim.x + threadIdx.x;
  if (e < N_EDGES) {
    int pos = atomicAdd(&cursor[dst[e]], 1);
    srcs[pos] = src[e];
  }
}

// ---- aggregation layer 1: wave/node, 4 sequential head passes (L2-resident) -
__global__ __launch_bounds__(256) void k_agg1(const _Float16* __restrict__ h,
                                              const float* __restrict__ al_s,
                                              const float* __restrict__ al_d,
                                              const int* __restrict__ offs,
                                              const int* __restrict__ srcs,
                                              const float* __restrict__ b1,
                                              _Float16* __restrict__ hm) {
  __shared__ int s_src[4][64];
  __shared__ float s_p[4][64];
  const int wv = threadIdx.x >> 6;
  const int lane = threadIdx.x & 63;
  const int head = blockIdx.x / 5000;          // monotonic: pass-per-head
  const int n = (blockIdx.x % 5000) * 4 + wv;
  const float adn = al_d[n * HEADS + head];
  const float pself = __expf(lrelu(al_s[n * HEADS + head] + adn));
  const int cb = head * HID + lane * 2;

  half2v hv = *(const half2v*)(h + (size_t)n * HC + cb);
  float den = pself;
  float a0 = pself * (float)hv[0], a1 = pself * (float)hv[1];

  const int beg = offs[n], end = offs[n + 1];
  for (int base = beg; base < end; base += 64) {
    const int m = min(64, end - base);
    if (lane < m) {
      int s = srcs[base + lane];
      s_src[wv][lane] = s;
      s_p[wv][lane] = __expf(lrelu(al_s[s * HEADS + head] + adn));
    }
    __builtin_amdgcn_wave_barrier();
    for (int qq = 0; qq < m; qq++) {
      int s = s_src[wv][qq];                    // uniform LDS broadcast
      float p = s_p[wv][qq];
      half2v v = *(const half2v*)(h + (size_t)s * HC + cb);
      den += p;
      a0 += p * (float)v[0];
      a1 += p * (float)v[1];
    }
    __builtin_amdgcn_wave_barrier();
  }
  const float inv = 1.f / den;
  float2 bb = *(const float2*)(b1 + cb);
  float o0 = a0 * inv + bb.x, o1 = a1 * inv + bb.y;
  o0 = o0 > 0.f ? o0 : __expf(o0) - 1.f;        // ELU
  o1 = o1 > 0.f ? o1 : __expf(o1) - 1.f;
  half2v ov; ov[0] = (_Float16)o0; ov[1] = (_Float16)o1;
  *(half2v*)(hm + (size_t)n * HC + cb) = ov;
}

// ------- GEMM2 (MFMA fp16) + fused layer-2 logits: zpre = hm @ W2 -----------
// M-tile 64 (wave per 16 rows), N = 32 (2 MFMA frags), whole w2t in LDS.
__global__ __launch_bounds__(256) void k_gemm2_mfma(const _Float16* __restrict__ hm,
                                                    const _Float16* __restrict__ w2t,
                                                    const float* __restrict__ a_s2,
                                                    const float* __restrict__ a_d2,
                                                    float* __restrict__ zpre,
                                                    float* __restrict__ al_s2,
                                                    float* __restrict__ al_d2) {
  __shared__ _Float16 Bs[32 * 520];   // [n][k], row pad 520 halves
  __shared__ _Float16 As[64 * 136];   // [m][k-tile 128], row pad 136
  const int tid = threadIdx.x;
  const int lane = tid & 63;
  const int w = tid >> 6;
  const int bm = blockIdx.x * 64;
  const int n15 = lane & 15;
  const int q = lane >> 4;

  // stage all of w2t (32x512 halves)
#pragma unroll
  for (int it = 0; it < 8; it++) {
    int idx = (tid + it * 256) * 8;
    int n = idx >> 9, k = idx & 511;
    *(half8*)&Bs[n * 520 + k] = *(const half8*)(w2t + idx);
  }

  f32x4 acc0 = {0.f, 0.f, 0.f, 0.f}, acc1 = {0.f, 0.f, 0.f, 0.f};
  for (int kt = 0; kt < HC; kt += 128) {
#pragma unroll
    for (int p = 0; p < 4; p++) {
      int row = (tid >> 4) + p * 16;
      int kof = (tid & 15) * 8;
      int gm = bm + row;
      half8 v = {};
      if (gm < N_NODES) v = *(const half8*)(hm + (size_t)gm * HC + kt + kof);
      *(half8*)&As[row * 136 + kof] = v;
    }
    __syncthreads();
#pragma unroll
    for (int ks = 0; ks < 128; ks += 32) {
      half8 af = *(const half8*)&As[(w * 16 + n15) * 136 + ks + q * 8];
      half8 b0 = *(const half8*)&Bs[n15 * 520 + kt + ks + q * 8];
      half8 b1 = *(const half8*)&Bs[(16 + n15) * 520 + kt + ks + q * 8];
      acc0 = __builtin_amdgcn_mfma_f32_16x16x32_f16(af, b0, acc0, 0, 0, 0);
      acc1 = __builtin_amdgcn_mfma_f32_16x16x32_f16(af, b1, acc1, 0, 0, 0);
    }
    __syncthreads();
  }
  // epilogue: C/D col=lane&15 (n), row=q*4+r. Write zpre + fused a-dots.
  const float asn0 = (n15 < OUT_CH) ? a_s2[n15] : 0.f;
  const float asn1 = (n15 + 16 < OUT_CH) ? a_s2[n15 + 16] : 0.f;
  const float adn0 = (n15 < OUT_CH) ? a_d2[n15] : 0.f;
  const float adn1 = (n15 + 16 < OUT_CH) ? a_d2[n15 + 16] : 0.f;
#pragma unroll
  for (int r = 0; r < 4; r++) {
    const int gm = bm + w * 16 + q * 4 + r;
    const bool ok = gm < N_NODES;
    if (ok) {
      zpre[(size_t)gm * OUT_CH + n15] = acc0[r];
      if (n15 + 16 < OUT_CH) zpre[(size_t)gm * OUT_CH + n15 + 16] = acc1[r];
    }
    float s = acc0[r] * asn0 + acc1[r] * asn1;
    float d = acc0[r] * adn0 + acc1[r] * adn1;
#pragma unroll
    for (int off = 8; off; off >>= 1) {
      s += __shfl_xor(s, off);
      d += __shfl_xor(d, off);
    }
    if (n15 == 0 && ok) {
      al_s2[gm] = s;
      al_d2[gm] = d;
    }
  }
}

// ---------- aggregation layer 2, fused softmax -> z (d_out) -----------------
__global__ __launch_bounds__(256) void k_agg2(const float* __restrict__ zpre,
                                              const float* __restrict__ al_s2,
                                              const float* __restrict__ al_d2,
                                              const int* __restrict__ offs,
                                              const int* __restrict__ srcs,
                                              const float* __restrict__ b2,
                                              float* __restrict__ zout) {
  const int n = blockIdx.x * 4 + (threadIdx.x >> 6);
  const int lane = threadIdx.x & 63;
  if (n >= N_NODES) return;
  const float ad2n = al_d2[n];
  const float pself = __expf(lrelu(al_s2[n] + ad2n));
  float zv = (lane < OUT_CH) ? zpre[(size_t)n * OUT_CH + lane] : 0.f;
  float acc = pself * zv;
  float den = pself;
  const int beg = offs[n], end = offs[n + 1];
  for (int base = beg; base < end; base += 64) {
    int m = min(64, end - base);
    int ssrc = (lane < m) ? srcs[base + lane] : 0;
    float pp = (lane < m) ? __expf(lrelu(al_s2[ssrc] + ad2n)) : 0.f;
    for (int qq = 0; qq < m; qq++) {
      int s = __shfl(ssrc, qq);
      float p = __shfl(pp, qq);
      den += p;
      float sv = (lane < OUT_CH) ? zpre[(size_t)s * OUT_CH + lane] : 0.f;
      acc += p * sv;
    }
  }
  if (lane < OUT_CH) zout[(size_t)n * OUT_CH + lane] = acc / den + b2[lane];
}

// ---------------- decoder: x_hat = z @ Wd + bd, 64 rows/block ---------------
__global__ __launch_bounds__(256) void k_dec(const float* __restrict__ z,
                                             const float* __restrict__ Wd,
                                             const float* __restrict__ bd,
                                             float* __restrict__ xhat) {
  __shared__ float zs[64][32];
  const int tid = threadIdx.x;
  const int c = tid * 2;
  float wd0[32], wd1[32];
#pragma unroll
  for (int k = 0; k < OUT_CH; k++) {
    float2 wv = *(const float2*)(Wd + (size_t)k * IN_CH + c);
    wd0[k] = wv.x; wd1[k] = wv.y;
  }
  wd0[30] = wd0[31] = wd1[30] = wd1[31] = 0.f;
  const int n0 = blockIdx.x * 64;
  for (int idx = tid; idx < 64 * 32; idx += 256) {
    int r = idx >> 5, cc = idx & 31;
    int row = n0 + r;
    zs[r][cc] = (cc < OUT_CH && row < N_NODES) ? z[(size_t)row * OUT_CH + cc] : 0.f;
  }
  __syncthreads();
  const float b0 = bd[c], b1v = bd[c + 1];
  for (int i = 0; i < 64; i++) {
    int row = n0 + i;
    if (row >= N_NODES) break;
    float a0 = b0, a1 = b1v;
#pragma unroll
    for (int k4 = 0; k4 < 8; k4++) {
      float4 zv = *(const float4*)&zs[i][k4 * 4];   // broadcast b128
      a0 += zv.x * wd0[k4 * 4 + 0] + zv.y * wd0[k4 * 4 + 1] +
            zv.z * wd0[k4 * 4 + 2] + zv.w * wd0[k4 * 4 + 3];
      a1 += zv.x * wd1[k4 * 4 + 0] + zv.y * wd1[k4 * 4 + 1] +
            zv.z * wd1[k4 * 4 + 2] + zv.w * wd1[k4 * 4 + 3];
    }
    *(float2*)(xhat + (size_t)row * IN_CH + c) = make_float2(a0, a1);
  }
}

// ----------------------------------------------------------------------------
extern "C" void kernel_launch(void* const* d_in, const int* in_sizes, int n_in,
                              void* d_out, int out_size, void* d_ws, size_t ws_size,
                              hipStream_t stream) {
  const float* x    = (const float*)d_in[0];
  const int*   ei   = (const int*)d_in[1];
  const float* W1   = (const float*)d_in[2];
  const float* a_s1 = (const float*)d_in[3];
  const float* a_d1 = (const float*)d_in[4];
  const float* b1   = (const float*)d_in[5];
  const float* W2   = (const float*)d_in[6];
  const float* a_s2 = (const float*)d_in[7];
  const float* a_d2 = (const float*)d_in[8];
  const float* b2   = (const float*)d_in[9];
  const float* Wd   = (const float*)d_in[10];
  const float* bd   = (const float*)d_in[11];

  float* xhat = (float*)d_out;
  float* zout = xhat + (size_t)N_NODES * IN_CH;

  const int* srcv = ei;
  const int* dstv = ei + N_EDGES;

  char* w = (char*)d_ws;
  auto alloc = [&](size_t bytes) {
    void* p = (void*)w;
    w += (bytes + 255) & ~(size_t)255;
    return p;
  };
  _Float16* xh   = (_Float16*)alloc((size_t)M_PAD * IN_CH * 2);
  _Float16* w1t  = (_Float16*)alloc((size_t)HC * IN_CH * 2);
  _Float16* w2t  = (_Float16*)alloc((size_t)32 * HC * 2);
  _Float16* h    = (_Float16*)alloc((size_t)N_NODES * HC * 2);
  _Float16* hm   = (_Float16*)alloc((size_t)N_NODES * HC * 2);
  float* zpre  = (float*)alloc((size_t)N_NODES * OUT_CH * 4);
  float* al_s1v= (float*)alloc((size_t)N_NODES * HEADS * 4);
  float* al_d1v= (float*)alloc((size_t)N_NODES * HEADS * 4);
  float* al_s2v= (float*)alloc((size_t)N_NODES * 4);
  float* al_d2v= (float*)alloc((size_t)N_NODES * 4);
  int*   cnt   = (int*)alloc((size_t)N_NODES * 4);
  int*   offs  = (int*)alloc((size_t)(N_NODES + 1) * 4);
  int*   cursor= (int*)alloc((size_t)N_NODES * 4);
  int*   srcs  = (int*)alloc((size_t)N_EDGES * 4);
  int*   part  = (int*)alloc((size_t)PARTS * 4);

  const int EB = (N_EDGES + 255) / 256;

  k_cast_x<<<(M_PAD * IN_CH / 4 + 255) / 256, 256, 0, stream>>>(x, xh);
  k_cast_w1t<<<dim3(IN_CH / 64, HC / 64), 256, 0, stream>>>(W1, w1t);
  k_cast_w2t<<<(32 * HC + 255) / 256, 256, 0, stream>>>(W2, w2t);
  k_gemm1_mfma<<<dim3(M_PAD / 128, HC / 128), 256, 0, stream>>>(xh, w1t, h);
  k_al1<<<256, 256, 0, stream>>>(h, a_s1, a_d1, al_s1v, al_d1v);
  // CSR build
  hipMemsetAsync(cnt, 0, (size_t)N_NODES * 4, stream);
  k_count<<<EB, 256, 0, stream>>>(dstv, cnt);
  k_scan_part<<<PARTS, 256, 0, stream>>>(cnt, part);
  k_scan_tops<<<1, 128, 0, stream>>>(part, offs);
  k_scan_final<<<PARTS, 256, 0, stream>>>(cnt, part, offs, cursor);
  k_scatter<<<EB, 256, 0, stream>>>(srcv, dstv, cursor, srcs);
  // fused aggregate layer 1: 4 sequential head passes
  k_agg1<<<5000 * HEADS, 256, 0, stream>>>(h, al_s1v, al_d1v, offs, srcs, b1, hm);
  // GEMM2 (MFMA) + fused layer-2 logits
  k_gemm2_mfma<<<(N_NODES + 63) / 64, 256, 0, stream>>>(hm, w2t, a_s2, a_d2, zpre,
                                                        al_s2v, al_d2v);
  // aggregate layer 2 -> z
  k_agg2<<<(N_NODES + 3) / 4, 256, 0, stream>>>(zpre, al_s2v, al_d2v, offs, srcs, b2, zout);
  // decoder
  k_dec<<<(N_NODES + 63) / 64, 256, 0, stream>>>(zout, Wd, bd, xhat);
}

// Round 6
// 278.942 us; speedup vs baseline: 2.3930x; 1.0787x over previous
//
#include <hip/hip_runtime.h>
#include <hip/hip_bf16.h>
#include <stdint.h>

#define N_NODES 20000
#define N_EDGES 320000
#define IN_CH 512
#define HID 128
#define HEADS 4
#define HC 512          // HEADS*HID
#define OUT_CH 30
#define NEG_SLOPE 0.2f
#define M_PAD 20096     // 157 * 128

typedef _Float16 half8 __attribute__((ext_vector_type(8)));
typedef _Float16 half4v __attribute__((ext_vector_type(4)));
typedef _Float16 half2v __attribute__((ext_vector_type(2)));
typedef float f32x4 __attribute__((ext_vector_type(4)));

static __device__ __forceinline__ float lrelu(float e) { return e > 0.f ? e : NEG_SLOPE * e; }

// async global->LDS, 16B per lane; dest = wave-uniform base + lane*16
static __device__ __forceinline__ void gload16(const void* gsrc, void* ldst) {
  __builtin_amdgcn_global_load_lds(
      (const __attribute__((address_space(1))) uint32_t*)gsrc,
      (__attribute__((address_space(3))) uint32_t*)ldst,
      16, 0, 0);
}

// ------------------------- cast x -> fp16 (padded rows zeroed) ---------------
__global__ __launch_bounds__(256) void k_cast_x(const float* __restrict__ x,
                                                _Float16* __restrict__ xh) {
  int i = blockIdx.x * blockDim.x + threadIdx.x;
  int base = i * 4;
  int row = base >> 9;
  half4v o;
  if (row < N_NODES) {
    float4 v = *(const float4*)(x + (size_t)base);
    o[0] = (_Float16)v.x; o[1] = (_Float16)v.y; o[2] = (_Float16)v.z; o[3] = (_Float16)v.w;
  } else {
    o[0] = o[1] = o[2] = o[3] = (_Float16)0.f;
  }
  *(half4v*)(xh + (size_t)base) = o;
}

// ------------------- cast + transpose W1 [k][n] -> W1t fp16 [n][k] ----------
__global__ __launch_bounds__(256) void k_cast_w1t(const float* __restrict__ W1,
                                                  _Float16* __restrict__ W1t) {
  __shared__ float t[64][65];
  const int bk = blockIdx.x * 64;
  const int bn = blockIdx.y * 64;
  const int tid = threadIdx.x;
#pragma unroll
  for (int it = 0; it < 16; it++) {
    int idx = tid + it * 256;
    int r = idx >> 6, c = idx & 63;
    t[r][c] = W1[(size_t)(bk + r) * HC + bn + c];
  }
  __syncthreads();
#pragma unroll
  for (int it = 0; it < 16; it++) {
    int idx = tid + it * 256;
    int rn = idx >> 6, ck = idx & 63;
    W1t[(size_t)(bn + rn) * IN_CH + bk + ck] = (_Float16)t[ck][rn];
  }
}

// ---------- cast W2 [512][30] fp32 -> w2t fp16 [32][512] (n-major, padded) --
__global__ __launch_bounds__(256) void k_cast_w2t(const float* __restrict__ W2,
                                                  _Float16* __restrict__ w2t) {
  int idx = blockIdx.x * blockDim.x + threadIdx.x;   // over 32*512
  if (idx >= 32 * 512) return;
  int n = idx >> 9, k = idx & 511;
  w2t[idx] = (n < OUT_CH) ? (_Float16)W2[(size_t)k * OUT_CH + n] : (_Float16)0.f;
}

// ---------------- GEMM1 (MFMA fp16): h = x @ W1, output fp16 ----------------
// LDS: As/Bs for mainloop, then reused as Cs (stride 136) for coalesced epilogue.
__global__ __launch_bounds__(256) void k_gemm1_mfma(const _Float16* __restrict__ A,
                                                    const _Float16* __restrict__ Bt,
                                                    _Float16* __restrict__ C) {
  __shared__ _Float16 smem[128 * 136];   // 34816 B
  _Float16* As = smem;                    // 128*64
  _Float16* Bs = smem + 128 * 64;         // 128*64
  _Float16* Cs = smem;                    // reused after final barrier
  const int tid = threadIdx.x;
  const int lane = tid & 63;
  const int w = tid >> 6;
  const int bm = blockIdx.x * 128;
  const int bn = blockIdx.y * 128;

  const int lrow = lane >> 3;
  const int schunk = (lane & 7) ^ lrow;

  const int wm = w >> 1, wn = w & 1;
  const int r15 = lane & 15;
  const int q = lane >> 4;
  const int a_row0 = wm * 64 + r15;
  const int b_row0 = wn * 64 + r15;

  f32x4 acc[4][4];
  const f32x4 zero = {0.f, 0.f, 0.f, 0.f};
#pragma unroll
  for (int i = 0; i < 4; i++)
#pragma unroll
    for (int j = 0; j < 4; j++) acc[i][j] = zero;

  for (int kb = 0; kb < 8; kb++) {
    const int kof = kb * 64 + schunk * 8;
#pragma unroll
    for (int t = 0; t < 4; t++) {
      const int row = w * 32 + t * 8;
      gload16(A + (size_t)(bm + row + lrow) * IN_CH + kof, (void*)(As + row * 64));
      gload16(Bt + (size_t)(bn + row + lrow) * IN_CH + kof, (void*)(Bs + row * 64));
    }
    __syncthreads();
#pragma unroll
    for (int s = 0; s < 2; s++) {
      const int cs = ((s * 4 + q) ^ (lane & 7)) * 8;
      half8 af[4], bf[4];
#pragma unroll
      for (int i = 0; i < 4; i++) af[i] = *(const half8*)&As[(a_row0 + i * 16) * 64 + cs];
#pragma unroll
      for (int j = 0; j < 4; j++) bf[j] = *(const half8*)&Bs[(b_row0 + j * 16) * 64 + cs];
#pragma unroll
      for (int i = 0; i < 4; i++)
#pragma unroll
        for (int j = 0; j < 4; j++)
          acc[i][j] = __builtin_amdgcn_mfma_f32_16x16x32_f16(af[i], bf[j], acc[i][j], 0, 0, 0);
    }
    __syncthreads();
  }
  // epilogue: bounce through LDS, then fully-coalesced half8 stores
#pragma unroll
  for (int i = 0; i < 4; i++)
#pragma unroll
    for (int j = 0; j < 4; j++)
#pragma unroll
      for (int r = 0; r < 4; r++) {
        const int row = wm * 64 + i * 16 + q * 4 + r;
        const int col = wn * 64 + j * 16 + r15;
        Cs[row * 136 + col] = (_Float16)acc[i][j][r];
      }
  __syncthreads();
#pragma unroll
  for (int it = 0; it < 8; it++) {
    int cidx = tid + it * 256;
    int row = cidx >> 4, c16 = cidx & 15;
    int gm = bm + row;
    if (gm < N_NODES)
      *(half8*)(C + (size_t)gm * HC + bn + c16 * 8) = *(const half8*)&Cs[row * 136 + c16 * 8];
  }
}

// ------- per-node attention logits layer 1: grid-stride waves, regs for a ---
__global__ __launch_bounds__(256) void k_al1(const _Float16* __restrict__ h,
                                             const float* __restrict__ a_src,
                                             const float* __restrict__ a_dst,
                                             float* __restrict__ al_s,
                                             float* __restrict__ al_d) {
  const int lane = threadIdx.x & 63;
  const int wid = (blockIdx.x * 256 + threadIdx.x) >> 6;   // 0..1023
  const int c0 = lane * 8;
  float as[8], ad[8];
#pragma unroll
  for (int j = 0; j < 8; j++) {
    as[j] = a_src[c0 + j];
    ad[j] = a_dst[c0 + j];
  }
  for (int n = wid; n < N_NODES; n += 1024) {
    half8 hv = *(const half8*)(h + (size_t)n * HC + c0);
    float s = 0.f, d = 0.f;
#pragma unroll
    for (int j = 0; j < 8; j++) {
      float hf = (float)hv[j];
      s += hf * as[j];
      d += hf * ad[j];
    }
#pragma unroll
    for (int off = 8; off; off >>= 1) {
      s += __shfl_down(s, off);
      d += __shfl_down(d, off);
    }
    if ((lane & 15) == 0) {
      al_s[n * HEADS + (lane >> 4)] = s;
      al_d[n * HEADS + (lane >> 4)] = d;
    }
  }
}

// ------------------------------- CSR build ----------------------------------
#define PARTS 79   // ceil(20000/256)
__global__ void k_count(const int* __restrict__ dst, int* __restrict__ cnt) {
  int e = blockIdx.x * blockDim.x + threadIdx.x;
  if (e < N_EDGES) atomicAdd(&cnt[dst[e]], 1);
}
__global__ __launch_bounds__(256) void k_scan_part(const int* __restrict__ cnt,
                                                   int* __restrict__ part) {
  __shared__ int ws[4];
  int i = blockIdx.x * 256 + threadIdx.x;
  int v = (i < N_NODES) ? cnt[i] : 0;
  int lane = threadIdx.x & 63;
#pragma unroll
  for (int off = 32; off; off >>= 1) v += __shfl_down(v, off);
  if (lane == 0) ws[threadIdx.x >> 6] = v;
  __syncthreads();
  if (threadIdx.x == 0) part[blockIdx.x] = ws[0] + ws[1] + ws[2] + ws[3];
}
__global__ __launch_bounds__(128) void k_scan_tops(int* __restrict__ part,
                                                   int* __restrict__ offs) {
  __shared__ int buf[128];
  int t = threadIdx.x;
  int v = (t < PARTS) ? part[t] : 0;
  buf[t] = v;
  __syncthreads();
#pragma unroll
  for (int off = 1; off < 128; off <<= 1) {
    int x = (t >= off) ? buf[t - off] : 0;
    __syncthreads();
    buf[t] += x;
    __syncthreads();
  }
  if (t < PARTS) part[t] = buf[t] - v;
  if (t == PARTS - 1) offs[N_NODES] = buf[t];
}
__global__ __launch_bounds__(256) void k_scan_final(const int* __restrict__ cnt,
                                                    const int* __restrict__ part,
                                                    int* __restrict__ offs,
                                                    int* __restrict__ cursor) {
  __shared__ int buf[256];
  int i = blockIdx.x * 256 + threadIdx.x;
  int t = threadIdx.x;
  int v = (i < N_NODES) ? cnt[i] : 0;
  buf[t] = v;
  __syncthreads();
#pragma unroll
  for (int off = 1; off < 256; off <<= 1) {
    int x = (t >= off) ? buf[t - off] : 0;
    __syncthreads();
    buf[t] += x;
    __syncthreads();
  }
  if (i < N_NODES) {
    int ex = part[blockIdx.x] + buf[t] - v;
    offs[i] = ex;
    cursor[i] = ex;
  }
}
// scatter SOURCE ids directly
__global__ void k_scatter(const int* __restrict__ src, const int* __restrict__ dst,
                          int* __restrict__ cursor, int* __restrict__ srcs) {
  int e = blockIdx.x * blockDim.x + threadIdx.x;
  if (e < N_EDGES) {
    int pos = atomicAdd(&cursor[dst[e]], 1);
    srcs[pos] = src[e];
  }
}

// ---- aggregation layer 1: quarter-wave per node, 16B/lane, 4 head passes ---
__global__ __launch_bounds__(256) void k_agg1(const _Float16* __restrict__ h,
                                              const float* __restrict__ al_s,
                                              const float* __restrict__ al_d,
                                              const int* __restrict__ offs,
                                              const int* __restrict__ srcs,
                                              const float* __restrict__ b1,
                                              _Float16* __restrict__ hm) {
  __shared__ int2 s_sp[4][64];             // (src, p-bits) per wave
  const int wv = threadIdx.x >> 6;
  const int lane = threadIdx.x & 63;
  const int qq = lane >> 4;                // quarter = node within wave
  const int l16 = lane & 15;
  const int head = blockIdx.x / 1250;      // head-major: L2-resident slice pass
  const int n = (blockIdx.x % 1250) * 16 + wv * 4 + qq;
  const int cb = head * HID + l16 * 8;

  const float adn = al_d[n * HEADS + head];
  const float pself = __expf(lrelu(al_s[n * HEADS + head] + adn));

  half8 hv = *(const half8*)(h + (size_t)n * HC + cb);
  float acc[8];
  float den = pself;
#pragma unroll
  for (int j = 0; j < 8; j++) acc[j] = pself * (float)hv[j];

  const int beg = offs[n];
  const int cnt = offs[n + 1] - beg;
  int mx = cnt;
  mx = max(mx, __shfl_xor(mx, 16));
  mx = max(mx, __shfl_xor(mx, 32));

  for (int base = 0; base < mx; base += 16) {
    // stage 16 edges per quarter (branchless; invalid -> p=0, s=n)
    int s = n;
    float p = 0.f;
    if (base + l16 < cnt) {
      s = srcs[beg + base + l16];
      p = __expf(lrelu(al_s[s * HEADS + head] + adn));
    }
    s_sp[wv][lane] = make_int2(s, __float_as_int(p));
    __builtin_amdgcn_wave_barrier();
    const int m = min(16, cnt - base);     // quarter-uniform; <=0 skips
    for (int k = 0; k < m; k++) {
      int2 sp = s_sp[wv][qq * 16 + k];
      float pk = __int_as_float(sp.y);
      half8 v = *(const half8*)(h + (size_t)sp.x * HC + cb);
      den += pk;
#pragma unroll
      for (int j = 0; j < 8; j++) acc[j] += pk * (float)v[j];
    }
    __builtin_amdgcn_wave_barrier();
  }
  const float inv = 1.f / den;
  float4 bb0 = *(const float4*)(b1 + cb);
  float4 bb1 = *(const float4*)(b1 + cb + 4);
  float ob[8] = {bb0.x, bb0.y, bb0.z, bb0.w, bb1.x, bb1.y, bb1.z, bb1.w};
  half8 ov;
#pragma unroll
  for (int j = 0; j < 8; j++) {
    float o = acc[j] * inv + ob[j];
    o = o > 0.f ? o : __expf(o) - 1.f;      // ELU
    ov[j] = (_Float16)o;
  }
  *(half8*)(hm + (size_t)n * HC + cb) = ov;
}

// ------- GEMM2 (MFMA fp16) + fused layer-2 logits: zpre = hm @ W2 -----------
__global__ __launch_bounds__(256) void k_gemm2_mfma(const _Float16* __restrict__ hm,
                                                    const _Float16* __restrict__ w2t,
                                                    const float* __restrict__ a_s2,
                                                    const float* __restrict__ a_d2,
                                                    float* __restrict__ zpre,
                                                    float* __restrict__ al_s2,
                                                    float* __restrict__ al_d2) {
  __shared__ _Float16 Bs[32 * 520];
  __shared__ _Float16 As[64 * 136];
  const int tid = threadIdx.x;
  const int lane = tid & 63;
  const int w = tid >> 6;
  const int bm = blockIdx.x * 64;
  const int n15 = lane & 15;
  const int q = lane >> 4;

#pragma unroll
  for (int it = 0; it < 8; it++) {
    int idx = (tid + it * 256) * 8;
    int n = idx >> 9, k = idx & 511;
    *(half8*)&Bs[n * 520 + k] = *(const half8*)(w2t + idx);
  }

  f32x4 acc0 = {0.f, 0.f, 0.f, 0.f}, acc1 = {0.f, 0.f, 0.f, 0.f};
  for (int kt = 0; kt < HC; kt += 128) {
#pragma unroll
    for (int p = 0; p < 4; p++) {
      int row = (tid >> 4) + p * 16;
      int kof = (tid & 15) * 8;
      int gm = bm + row;
      half8 v = {};
      if (gm < N_NODES) v = *(const half8*)(hm + (size_t)gm * HC + kt + kof);
      *(half8*)&As[row * 136 + kof] = v;
    }
    __syncthreads();
#pragma unroll
    for (int ks = 0; ks < 128; ks += 32) {
      half8 af = *(const half8*)&As[(w * 16 + n15) * 136 + ks + q * 8];
      half8 b0 = *(const half8*)&Bs[n15 * 520 + kt + ks + q * 8];
      half8 b1 = *(const half8*)&Bs[(16 + n15) * 520 + kt + ks + q * 8];
      acc0 = __builtin_amdgcn_mfma_f32_16x16x32_f16(af, b0, acc0, 0, 0, 0);
      acc1 = __builtin_amdgcn_mfma_f32_16x16x32_f16(af, b1, acc1, 0, 0, 0);
    }
    __syncthreads();
  }
  const float asn0 = (n15 < OUT_CH) ? a_s2[n15] : 0.f;
  const float asn1 = (n15 + 16 < OUT_CH) ? a_s2[n15 + 16] : 0.f;
  const float adn0 = (n15 < OUT_CH) ? a_d2[n15] : 0.f;
  const float adn1 = (n15 + 16 < OUT_CH) ? a_d2[n15 + 16] : 0.f;
#pragma unroll
  for (int r = 0; r < 4; r++) {
    const int gm = bm + w * 16 + q * 4 + r;
    const bool ok = gm < N_NODES;
    if (ok) {
      zpre[(size_t)gm * OUT_CH + n15] = acc0[r];
      if (n15 + 16 < OUT_CH) zpre[(size_t)gm * OUT_CH + n15 + 16] = acc1[r];
    }
    float s = acc0[r] * asn0 + acc1[r] * asn1;
    float d = acc0[r] * adn0 + acc1[r] * adn1;
#pragma unroll
    for (int off = 8; off; off >>= 1) {
      s += __shfl_xor(s, off);
      d += __shfl_xor(d, off);
    }
    if (n15 == 0 && ok) {
      al_s2[gm] = s;
      al_d2[gm] = d;
    }
  }
}

// ---- aggregation layer 2: half-wave per node, LDS staging -> z (d_out) -----
__global__ __launch_bounds__(256) void k_agg2(const float* __restrict__ zpre,
                                              const float* __restrict__ al_s2,
                                              const float* __restrict__ al_d2,
                                              const int* __restrict__ offs,
                                              const int* __restrict__ srcs,
                                              const float* __restrict__ b2,
                                              float* __restrict__ zout) {
  __shared__ int2 s_sp[4][64];
  const int wv = threadIdx.x >> 6;
  const int lane = threadIdx.x & 63;
  const int hh = lane >> 5;               // half = node within wave
  const int l32 = lane & 31;
  const int n = blockIdx.x * 8 + wv * 2 + hh;   // grid 2500 -> exactly 20000
  const float ad2n = al_d2[n];
  const float pself = __expf(lrelu(al_s2[n] + ad2n));
  const bool act = l32 < OUT_CH;
  float zv = act ? zpre[(size_t)n * OUT_CH + l32] : 0.f;
  float acc = pself * zv;
  float den = pself;

  const int beg = offs[n];
  const int cnt = offs[n + 1] - beg;
  int mx = max(cnt, __shfl_xor(cnt, 32));

  for (int base = 0; base < mx; base += 32) {
    int s = n;
    float p = 0.f;
    if (base + l32 < cnt) {
      s = srcs[beg + base + l32];
      p = __expf(lrelu(al_s2[s] + ad2n));
    }
    s_sp[wv][lane] = make_int2(s, __float_as_int(p));
    __builtin_amdgcn_wave_barrier();
    const int m = min(32, cnt - base);
    for (int k = 0; k < m; k++) {
      int2 sp = s_sp[wv][hh * 32 + k];
      float pk = __int_as_float(sp.y);
      float sv = act ? zpre[(size_t)sp.x * OUT_CH + l32] : 0.f;
      den += pk;
      acc += pk * sv;
    }
    __builtin_amdgcn_wave_barrier();
  }
  if (act) zout[(size_t)n * OUT_CH + l32] = acc / den + b2[l32];
}

// ------- decoder: x_hat = z @ Wd + bd, 64 rows x 256 cols per block ---------
__global__ __launch_bounds__(256) void k_dec(const float* __restrict__ z,
                                             const float* __restrict__ Wd,
                                             const float* __restrict__ bd,
                                             float* __restrict__ xhat) {
  __shared__ float zs[64][32];
  const int tid = threadIdx.x;
  const int c = blockIdx.y * 256 + tid;   // one column per thread
  float wd[32];
#pragma unroll
  for (int k = 0; k < OUT_CH; k++) wd[k] = Wd[(size_t)k * IN_CH + c];
  wd[30] = wd[31] = 0.f;
  const int n0 = blockIdx.x * 64;
  for (int idx = tid; idx < 64 * 32; idx += 256) {
    int r = idx >> 5, cc = idx & 31;
    int row = n0 + r;
    zs[r][cc] = (cc < OUT_CH && row < N_NODES) ? z[(size_t)row * OUT_CH + cc] : 0.f;
  }
  __syncthreads();
  const float b0 = bd[c];
  for (int i = 0; i < 64; i++) {
    int row = n0 + i;
    if (row >= N_NODES) break;
    float a0 = b0;
#pragma unroll
    for (int k4 = 0; k4 < 8; k4++) {
      float4 zv = *(const float4*)&zs[i][k4 * 4];
      a0 += zv.x * wd[k4 * 4 + 0] + zv.y * wd[k4 * 4 + 1] +
            zv.z * wd[k4 * 4 + 2] + zv.w * wd[k4 * 4 + 3];
    }
    xhat[(size_t)row * IN_CH + c] = a0;
  }
}

// ----------------------------------------------------------------------------
extern "C" void kernel_launch(void* const* d_in, const int* in_sizes, int n_in,
                              void* d_out, int out_size, void* d_ws, size_t ws_size,
                              hipStream_t stream) {
  const float* x    = (const float*)d_in[0];
  const int*   ei   = (const int*)d_in[1];
  const float* W1   = (const float*)d_in[2];
  const float* a_s1 = (const float*)d_in[3];
  const float* a_d1 = (const float*)d_in[4];
  const float* b1   = (const float*)d_in[5];
  const float* W2   = (const float*)d_in[6];
  const float* a_s2 = (const float*)d_in[7];
  const float* a_d2 = (const float*)d_in[8];
  const float* b2   = (const float*)d_in[9];
  const float* Wd   = (const float*)d_in[10];
  const float* bd   = (const float*)d_in[11];

  float* xhat = (float*)d_out;
  float* zout = xhat + (size_t)N_NODES * IN_CH;

  const int* srcv = ei;
  const int* dstv = ei + N_EDGES;

  char* w = (char*)d_ws;
  auto alloc = [&](size_t bytes) {
    void* p = (void*)w;
    w += (bytes + 255) & ~(size_t)255;
    return p;
  };
  _Float16* xh   = (_Float16*)alloc((size_t)M_PAD * IN_CH * 2);
  _Float16* w1t  = (_Float16*)alloc((size_t)HC * IN_CH * 2);
  _Float16* w2t  = (_Float16*)alloc((size_t)32 * HC * 2);
  _Float16* h    = (_Float16*)alloc((size_t)N_NODES * HC * 2);
  _Float16* hm   = (_Float16*)alloc((size_t)N_NODES * HC * 2);
  float* zpre  = (float*)alloc((size_t)N_NODES * OUT_CH * 4);
  float* al_s1v= (float*)alloc((size_t)N_NODES * HEADS * 4);
  float* al_d1v= (float*)alloc((size_t)N_NODES * HEADS * 4);
  float* al_s2v= (float*)alloc((size_t)N_NODES * 4);
  float* al_d2v= (float*)alloc((size_t)N_NODES * 4);
  int*   cnt   = (int*)alloc((size_t)N_NODES * 4);
  int*   offs  = (int*)alloc((size_t)(N_NODES + 1) * 4);
  int*   cursor= (int*)alloc((size_t)N_NODES * 4);
  int*   srcs  = (int*)alloc((size_t)N_EDGES * 4);
  int*   part  = (int*)alloc((size_t)PARTS * 4);

  const int EB = (N_EDGES + 255) / 256;

  k_cast_x<<<(M_PAD * IN_CH / 4 + 255) / 256, 256, 0, stream>>>(x, xh);
  k_cast_w1t<<<dim3(IN_CH / 64, HC / 64), 256, 0, stream>>>(W1, w1t);
  k_cast_w2t<<<(32 * HC + 255) / 256, 256, 0, stream>>>(W2, w2t);
  k_gemm1_mfma<<<dim3(M_PAD / 128, HC / 128), 256, 0, stream>>>(xh, w1t, h);
  k_al1<<<256, 256, 0, stream>>>(h, a_s1, a_d1, al_s1v, al_d1v);
  // CSR build
  hipMemsetAsync(cnt, 0, (size_t)N_NODES * 4, stream);
  k_count<<<EB, 256, 0, stream>>>(dstv, cnt);
  k_scan_part<<<PARTS, 256, 0, stream>>>(cnt, part);
  k_scan_tops<<<1, 128, 0, stream>>>(part, offs);
  k_scan_final<<<PARTS, 256, 0, stream>>>(cnt, part, offs, cursor);
  k_scatter<<<EB, 256, 0, stream>>>(srcv, dstv, cursor, srcs);
  // aggregate layer 1: quarter-wave per node, 4 sequential head passes
  k_agg1<<<1250 * HEADS, 256, 0, stream>>>(h, al_s1v, al_d1v, offs, srcs, b1, hm);
  // GEMM2 (MFMA) + fused layer-2 logits
  k_gemm2_mfma<<<(N_NODES + 63) / 64, 256, 0, stream>>>(hm, w2t, a_s2, a_d2, zpre,
                                                        al_s2v, al_d2v);
  // aggregate layer 2 -> z
  k_agg2<<<N_NODES / 8, 256, 0, stream>>>(zpre, al_s2v, al_d2v, offs, srcs, b2, zout);
  // decoder
  k_dec<<<dim3((N_NODES + 63) / 64, 2), 256, 0, stream>>>(zout, Wd, bd, xhat);
}

// Round 7
// 266.995 us; speedup vs baseline: 2.5001x; 1.0447x over previous
//
#include <hip/hip_runtime.h>
#include <hip/hip_bf16.h>
#include <stdint.h>

#define N_NODES 20000
#define N_EDGES 320000
#define IN_CH 512
#define HID 128
#define HEADS 4
#define HC 512          // HEADS*HID
#define OUT_CH 30
#define NEG_SLOPE 0.2f
#define M_PAD 20096     // 157 * 128

typedef _Float16 half8 __attribute__((ext_vector_type(8)));
typedef _Float16 half4v __attribute__((ext_vector_type(4)));
typedef float f32x4 __attribute__((ext_vector_type(4)));

static __device__ __forceinline__ float lrelu(float e) { return e > 0.f ? e : NEG_SLOPE * e; }

// async global->LDS, 16B per lane; dest = wave-uniform base + lane*16
static __device__ __forceinline__ void gload16(const void* gsrc, void* ldst) {
  __builtin_amdgcn_global_load_lds(
      (const __attribute__((address_space(1))) uint32_t*)gsrc,
      (__attribute__((address_space(3))) uint32_t*)ldst,
      16, 0, 0);
}

// ------------- cast x -> fp16 (padded rows zeroed) + zero cnt ---------------
__global__ __launch_bounds__(256) void k_cast_x(const float* __restrict__ x,
                                                _Float16* __restrict__ xh,
                                                int* __restrict__ cnt) {
  int i = blockIdx.x * blockDim.x + threadIdx.x;
  if (i < N_NODES) cnt[i] = 0;
  int base = i * 4;
  int row = base >> 9;
  half4v o;
  if (row < N_NODES) {
    float4 v = *(const float4*)(x + (size_t)base);
    o[0] = (_Float16)v.x; o[1] = (_Float16)v.y; o[2] = (_Float16)v.z; o[3] = (_Float16)v.w;
  } else {
    o[0] = o[1] = o[2] = o[3] = (_Float16)0.f;
  }
  *(half4v*)(xh + (size_t)base) = o;
}

// ---- combined weight prep: W1 -> w1t fp16 [n][k]; W2 -> w2t fp16 [32][512] -
__global__ __launch_bounds__(256) void k_prep_w(const float* __restrict__ W1,
                                                const float* __restrict__ W2,
                                                _Float16* __restrict__ W1t,
                                                _Float16* __restrict__ w2t) {
  __shared__ float t[64][65];
  const int b = blockIdx.x;
  const int tid = threadIdx.x;
  if (b < 64) {
    const int bk = (b & 7) * 64;
    const int bn = (b >> 3) * 64;
#pragma unroll
    for (int it = 0; it < 16; it++) {
      int idx = tid + it * 256;
      int r = idx >> 6, c = idx & 63;
      t[r][c] = W1[(size_t)(bk + r) * HC + bn + c];
    }
    __syncthreads();
#pragma unroll
    for (int it = 0; it < 16; it++) {
      int idx = tid + it * 256;
      int rn = idx >> 6, ck = idx & 63;
      W1t[(size_t)(bn + rn) * IN_CH + bk + ck] = (_Float16)t[ck][rn];
    }
  } else {
    int idx = (b - 64) * 256 + tid;       // over 32*512
    int n = idx >> 9, k = idx & 511;
    w2t[idx] = (n < OUT_CH) ? (_Float16)W2[(size_t)k * OUT_CH + n] : (_Float16)0.f;
  }
}

// ---- GEMM1 (MFMA fp16): h = x @ W1 (fp16 out) + FUSED layer-1 logits -------
// blockIdx.y == head (HID==128 column tile). Cs LDS tile reused for the dots.
__global__ __launch_bounds__(256) void k_gemm1_mfma(const _Float16* __restrict__ A,
                                                    const _Float16* __restrict__ Bt,
                                                    _Float16* __restrict__ C,
                                                    const float* __restrict__ a_src,
                                                    const float* __restrict__ a_dst,
                                                    float* __restrict__ al_s,
                                                    float* __restrict__ al_d) {
  __shared__ _Float16 smem[128 * 136];   // 34816 B
  _Float16* As = smem;                    // 128*64
  _Float16* Bs = smem + 128 * 64;         // 128*64
  _Float16* Cs = smem;                    // reused after final barrier
  const int tid = threadIdx.x;
  const int lane = tid & 63;
  const int w = tid >> 6;
  const int bm = blockIdx.x * 128;
  const int bn = blockIdx.y * 128;

  const int lrow = lane >> 3;
  const int schunk = (lane & 7) ^ lrow;

  const int wm = w >> 1, wn = w & 1;
  const int r15 = lane & 15;
  const int q = lane >> 4;
  const int a_row0 = wm * 64 + r15;
  const int b_row0 = wn * 64 + r15;

  f32x4 acc[4][4];
  const f32x4 zero = {0.f, 0.f, 0.f, 0.f};
#pragma unroll
  for (int i = 0; i < 4; i++)
#pragma unroll
    for (int j = 0; j < 4; j++) acc[i][j] = zero;

  for (int kb = 0; kb < 8; kb++) {
    const int kof = kb * 64 + schunk * 8;
#pragma unroll
    for (int t = 0; t < 4; t++) {
      const int row = w * 32 + t * 8;
      gload16(A + (size_t)(bm + row + lrow) * IN_CH + kof, (void*)(As + row * 64));
      gload16(Bt + (size_t)(bn + row + lrow) * IN_CH + kof, (void*)(Bs + row * 64));
    }
    __syncthreads();
#pragma unroll
    for (int s = 0; s < 2; s++) {
      const int cs = ((s * 4 + q) ^ (lane & 7)) * 8;
      half8 af[4], bf[4];
#pragma unroll
      for (int i = 0; i < 4; i++) af[i] = *(const half8*)&As[(a_row0 + i * 16) * 64 + cs];
#pragma unroll
      for (int j = 0; j < 4; j++) bf[j] = *(const half8*)&Bs[(b_row0 + j * 16) * 64 + cs];
#pragma unroll
      for (int i = 0; i < 4; i++)
#pragma unroll
        for (int j = 0; j < 4; j++)
          acc[i][j] = __builtin_amdgcn_mfma_f32_16x16x32_f16(af[i], bf[j], acc[i][j], 0, 0, 0);
    }
    __syncthreads();
  }
  // epilogue: bounce through LDS, coalesced half8 stores
#pragma unroll
  for (int i = 0; i < 4; i++)
#pragma unroll
    for (int j = 0; j < 4; j++)
#pragma unroll
      for (int r = 0; r < 4; r++) {
        const int row = wm * 64 + i * 16 + q * 4 + r;
        const int col = wn * 64 + j * 16 + r15;
        Cs[row * 136 + col] = (_Float16)acc[i][j][r];
      }
  __syncthreads();
#pragma unroll
  for (int it = 0; it < 8; it++) {
    int cidx = tid + it * 256;
    int row = cidx >> 4, c16 = cidx & 15;
    int gm = bm + row;
    if (gm < N_NODES)
      *(half8*)(C + (size_t)gm * HC + bn + c16 * 8) = *(const half8*)&Cs[row * 136 + c16 * 8];
  }
  // fused al1: this block's 128 cols == head slice. 2 threads/row, 64 cols each.
  const int head = blockIdx.y;
  const int row = tid >> 1;
  const int hf = tid & 1;
  const float* asp = a_src + head * HID + hf * 64;
  const float* adp = a_dst + head * HID + hf * 64;
  float s = 0.f, d = 0.f;
#pragma unroll
  for (int j8 = 0; j8 < 8; j8++) {
    half8 cv = *(const half8*)&Cs[row * 136 + hf * 64 + j8 * 8];
    float4 a0 = *(const float4*)(asp + j8 * 8);
    float4 a1 = *(const float4*)(asp + j8 * 8 + 4);
    float4 d0 = *(const float4*)(adp + j8 * 8);
    float4 d1 = *(const float4*)(adp + j8 * 8 + 4);
    float c0 = (float)cv[0], c1 = (float)cv[1], c2 = (float)cv[2], c3 = (float)cv[3];
    float c4 = (float)cv[4], c5 = (float)cv[5], c6 = (float)cv[6], c7 = (float)cv[7];
    s += c0 * a0.x + c1 * a0.y + c2 * a0.z + c3 * a0.w +
         c4 * a1.x + c5 * a1.y + c6 * a1.z + c7 * a1.w;
    d += c0 * d0.x + c1 * d0.y + c2 * d0.z + c3 * d0.w +
         c4 * d1.x + c5 * d1.y + c6 * d1.z + c7 * d1.w;
  }
  s += __shfl_xor(s, 1);
  d += __shfl_xor(d, 1);
  const int gm = bm + row;
  if (hf == 0 && gm < N_NODES) {
    al_s[gm * HEADS + head] = s;
    al_d[gm * HEADS + head] = d;
  }
}

// ------------------------------- CSR build ----------------------------------
#define PARTS 79   // ceil(20000/256)
__global__ void k_count(const int* __restrict__ dst, int* __restrict__ cnt) {
  int e = blockIdx.x * blockDim.x + threadIdx.x;
  if (e < N_EDGES) atomicAdd(&cnt[dst[e]], 1);
}
__global__ __launch_bounds__(256) void k_scan_part(const int* __restrict__ cnt,
                                                   int* __restrict__ part) {
  __shared__ int ws[4];
  int i = blockIdx.x * 256 + threadIdx.x;
  int v = (i < N_NODES) ? cnt[i] : 0;
  int lane = threadIdx.x & 63;
#pragma unroll
  for (int off = 32; off; off >>= 1) v += __shfl_down(v, off);
  if (lane == 0) ws[threadIdx.x >> 6] = v;
  __syncthreads();
  if (threadIdx.x == 0) part[blockIdx.x] = ws[0] + ws[1] + ws[2] + ws[3];
}
__global__ __launch_bounds__(128) void k_scan_tops(int* __restrict__ part,
                                                   int* __restrict__ offs) {
  __shared__ int buf[128];
  int t = threadIdx.x;
  int v = (t < PARTS) ? part[t] : 0;
  buf[t] = v;
  __syncthreads();
#pragma unroll
  for (int off = 1; off < 128; off <<= 1) {
    int x = (t >= off) ? buf[t - off] : 0;
    __syncthreads();
    buf[t] += x;
    __syncthreads();
  }
  if (t < PARTS) part[t] = buf[t] - v;
  if (t == PARTS - 1) offs[N_NODES] = buf[t];
}
__global__ __launch_bounds__(256) void k_scan_final(const int* __restrict__ cnt,
                                                    const int* __restrict__ part,
                                                    int* __restrict__ offs,
                                                    int* __restrict__ cursor) {
  __shared__ int buf[256];
  int i = blockIdx.x * 256 + threadIdx.x;
  int t = threadIdx.x;
  int v = (i < N_NODES) ? cnt[i] : 0;
  buf[t] = v;
  __syncthreads();
#pragma unroll
  for (int off = 1; off < 256; off <<= 1) {
    int x = (t >= off) ? buf[t - off] : 0;
    __syncthreads();
    buf[t] += x;
    __syncthreads();
  }
  if (i < N_NODES) {
    int ex = part[blockIdx.x] + buf[t] - v;
    offs[i] = ex;
    cursor[i] = ex;
  }
}
__global__ void k_scatter(const int* __restrict__ src, const int* __restrict__ dst,
                          int* __restrict__ cursor, int* __restrict__ srcs) {
  int e = blockIdx.x * blockDim.x + threadIdx.x;
  if (e < N_EDGES) {
    int pos = atomicAdd(&cursor[dst[e]], 1);
    srcs[pos] = src[e];
  }
}

// ---- agg layer 1: quarter-wave/node, reg+shfl staging, 4 loads in flight ---
__global__ __launch_bounds__(256) void k_agg1(const _Float16* __restrict__ h,
                                              const float* __restrict__ al_s,
                                              const float* __restrict__ al_d,
                                              const int* __restrict__ offs,
                                              const int* __restrict__ srcs,
                                              const float* __restrict__ b1,
                                              _Float16* __restrict__ hm) {
  const int lane = threadIdx.x & 63;
  const int qq = lane >> 4;                // quarter = node within wave
  const int l16 = lane & 15;
  const int head = blockIdx.x / 1250;      // head-major: L2-resident slice pass
  const int n = (blockIdx.x % 1250) * 16 + (threadIdx.x >> 6) * 4 + qq;
  const int cb = head * HID + l16 * 8;

  const float adn = al_d[n * HEADS + head];
  const float pself = __expf(lrelu(al_s[n * HEADS + head] + adn));

  half8 hv = *(const half8*)(h + (size_t)n * HC + cb);
  float acc[8];
  float den = pself;
#pragma unroll
  for (int j = 0; j < 8; j++) acc[j] = pself * (float)hv[j];

  const int beg = offs[n];
  const int cnt = offs[n + 1] - beg;
  int mx = cnt;
  mx = max(mx, __shfl_xor(mx, 16));
  mx = max(mx, __shfl_xor(mx, 32));
  const int kb = qq * 16;

  for (int base = 0; base < mx; base += 16) {
    // stage this lane's edge (branchless; invalid -> p=0, s=n)
    int sreg = n;
    float preg = 0.f;
    if (base + l16 < cnt) {
      sreg = srcs[beg + base + l16];
      preg = __expf(lrelu(al_s[sreg * HEADS + head] + adn));
    }
    int m = min(16, cnt - base);
    int m4 = (m + 3) & ~3;                 // <=0 skips loop
    for (int k = 0; k < m4; k += 4) {
      int s0 = __shfl(sreg, kb + k);
      int s1 = __shfl(sreg, kb + k + 1);
      int s2 = __shfl(sreg, kb + k + 2);
      int s3 = __shfl(sreg, kb + k + 3);
      float p0 = __shfl(preg, kb + k);
      float p1 = __shfl(preg, kb + k + 1);
      float p2 = __shfl(preg, kb + k + 2);
      float p3 = __shfl(preg, kb + k + 3);
      half8 v0 = *(const half8*)(h + (size_t)s0 * HC + cb);
      half8 v1 = *(const half8*)(h + (size_t)s1 * HC + cb);
      half8 v2 = *(const half8*)(h + (size_t)s2 * HC + cb);
      half8 v3 = *(const half8*)(h + (size_t)s3 * HC + cb);
      den += p0 + p1 + p2 + p3;
#pragma unroll
      for (int j = 0; j < 8; j++)
        acc[j] += p0 * (float)v0[j] + p1 * (float)v1[j] +
                  p2 * (float)v2[j] + p3 * (float)v3[j];
    }
  }
  const float inv = 1.f / den;
  float4 bb0 = *(const float4*)(b1 + cb);
  float4 bb1 = *(const float4*)(b1 + cb + 4);
  float ob[8] = {bb0.x, bb0.y, bb0.z, bb0.w, bb1.x, bb1.y, bb1.z, bb1.w};
  half8 ov;
#pragma unroll
  for (int j = 0; j < 8; j++) {
    float o = acc[j] * inv + ob[j];
    o = o > 0.f ? o : __expf(o) - 1.f;      // ELU
    ov[j] = (_Float16)o;
  }
  *(half8*)(hm + (size_t)n * HC + cb) = ov;
}

// ------- GEMM2 (MFMA fp16) + fused layer-2 logits: zpre = hm @ W2 -----------
__global__ __launch_bounds__(256) void k_gemm2_mfma(const _Float16* __restrict__ hm,
                                                    const _Float16* __restrict__ w2t,
                                                    const float* __restrict__ a_s2,
                                                    const float* __restrict__ a_d2,
                                                    float* __restrict__ zpre,
                                                    float* __restrict__ al_s2,
                                                    float* __restrict__ al_d2) {
  __shared__ _Float16 Bs[32 * 520];
  __shared__ _Float16 As[64 * 136];
  const int tid = threadIdx.x;
  const int lane = tid & 63;
  const int w = tid >> 6;
  const int bm = blockIdx.x * 64;
  const int n15 = lane & 15;
  const int q = lane >> 4;

#pragma unroll
  for (int it = 0; it < 8; it++) {
    int idx = (tid + it * 256) * 8;
    int n = idx >> 9, k = idx & 511;
    *(half8*)&Bs[n * 520 + k] = *(const half8*)(w2t + idx);
  }

  f32x4 acc0 = {0.f, 0.f, 0.f, 0.f}, acc1 = {0.f, 0.f, 0.f, 0.f};
  for (int kt = 0; kt < HC; kt += 128) {
#pragma unroll
    for (int p = 0; p < 4; p++) {
      int row = (tid >> 4) + p * 16;
      int kof = (tid & 15) * 8;
      int gm = bm + row;
      half8 v = {};
      if (gm < N_NODES) v = *(const half8*)(hm + (size_t)gm * HC + kt + kof);
      *(half8*)&As[row * 136 + kof] = v;
    }
    __syncthreads();
#pragma unroll
    for (int ks = 0; ks < 128; ks += 32) {
      half8 af = *(const half8*)&As[(w * 16 + n15) * 136 + ks + q * 8];
      half8 b0 = *(const half8*)&Bs[n15 * 520 + kt + ks + q * 8];
      half8 b1 = *(const half8*)&Bs[(16 + n15) * 520 + kt + ks + q * 8];
      acc0 = __builtin_amdgcn_mfma_f32_16x16x32_f16(af, b0, acc0, 0, 0, 0);
      acc1 = __builtin_amdgcn_mfma_f32_16x16x32_f16(af, b1, acc1, 0, 0, 0);
    }
    __syncthreads();
  }
  const float asn0 = (n15 < OUT_CH) ? a_s2[n15] : 0.f;
  const float asn1 = (n15 + 16 < OUT_CH) ? a_s2[n15 + 16] : 0.f;
  const float adn0 = (n15 < OUT_CH) ? a_d2[n15] : 0.f;
  const float adn1 = (n15 + 16 < OUT_CH) ? a_d2[n15 + 16] : 0.f;
#pragma unroll
  for (int r = 0; r < 4; r++) {
    const int gm = bm + w * 16 + q * 4 + r;
    const bool ok = gm < N_NODES;
    if (ok) {
      zpre[(size_t)gm * OUT_CH + n15] = acc0[r];
      if (n15 + 16 < OUT_CH) zpre[(size_t)gm * OUT_CH + n15 + 16] = acc1[r];
    }
    float s = acc0[r] * asn0 + acc1[r] * asn1;
    float d = acc0[r] * adn0 + acc1[r] * adn1;
#pragma unroll
    for (int off = 8; off; off >>= 1) {
      s += __shfl_xor(s, off);
      d += __shfl_xor(d, off);
    }
    if (n15 == 0 && ok) {
      al_s2[gm] = s;
      al_d2[gm] = d;
    }
  }
}

// ---- agg layer 2: half-wave/node, reg+shfl staging, 4 loads in flight ------
__global__ __launch_bounds__(256) void k_agg2(const float* __restrict__ zpre,
                                              const float* __restrict__ al_s2,
                                              const float* __restrict__ al_d2,
                                              const int* __restrict__ offs,
                                              const int* __restrict__ srcs,
                                              const float* __restrict__ b2,
                                              float* __restrict__ zout) {
  const int lane = threadIdx.x & 63;
  const int hh = lane >> 5;
  const int l32 = lane & 31;
  const int n = blockIdx.x * 8 + (threadIdx.x >> 6) * 2 + hh;  // grid 2500
  const float ad2n = al_d2[n];
  const float pself = __expf(lrelu(al_s2[n] + ad2n));
  const bool act = l32 < OUT_CH;
  float zv = act ? zpre[(size_t)n * OUT_CH + l32] : 0.f;
  float acc = pself * zv;
  float den = pself;

  const int beg = offs[n];
  const int cnt = offs[n + 1] - beg;
  int mx = max(cnt, __shfl_xor(cnt, 32));
  const int kb = hh * 32;

  for (int base = 0; base < mx; base += 32) {
    int sreg = n;
    float preg = 0.f;
    if (base + l32 < cnt) {
      sreg = srcs[beg + base + l32];
      preg = __expf(lrelu(al_s2[sreg] + ad2n));
    }
    int m = min(32, cnt - base);
    int m4 = (m + 3) & ~3;
    for (int k = 0; k < m4; k += 4) {
      int s0 = __shfl(sreg, kb + k);
      int s1 = __shfl(sreg, kb + k + 1);
      int s2 = __shfl(sreg, kb + k + 2);
      int s3 = __shfl(sreg, kb + k + 3);
      float p0 = __shfl(preg, kb + k);
      float p1 = __shfl(preg, kb + k + 1);
      float p2 = __shfl(preg, kb + k + 2);
      float p3 = __shfl(preg, kb + k + 3);
      float v0 = act ? zpre[(size_t)s0 * OUT_CH + l32] : 0.f;
      float v1 = act ? zpre[(size_t)s1 * OUT_CH + l32] : 0.f;
      float v2 = act ? zpre[(size_t)s2 * OUT_CH + l32] : 0.f;
      float v3 = act ? zpre[(size_t)s3 * OUT_CH + l32] : 0.f;
      den += p0 + p1 + p2 + p3;
      acc += p0 * v0 + p1 * v1 + p2 * v2 + p3 * v3;
    }
  }
  if (act) zout[(size_t)n * OUT_CH + l32] = acc / den + b2[l32];
}

// ------- decoder: x_hat = z @ Wd + bd, 64 rows x 256 cols per block ---------
__global__ __launch_bounds__(256) void k_dec(const float* __restrict__ z,
                                             const float* __restrict__ Wd,
                                             const float* __restrict__ bd,
                                             float* __restrict__ xhat) {
  __shared__ float zs[64][32];
  const int tid = threadIdx.x;
  const int c = blockIdx.y * 256 + tid;   // one column per thread
  float wd[32];
#pragma unroll
  for (int k = 0; k < OUT_CH; k++) wd[k] = Wd[(size_t)k * IN_CH + c];
  wd[30] = wd[31] = 0.f;
  const int n0 = blockIdx.x * 64;
  for (int idx = tid; idx < 64 * 32; idx += 256) {
    int r = idx >> 5, cc = idx & 31;
    int row = n0 + r;
    zs[r][cc] = (cc < OUT_CH && row < N_NODES) ? z[(size_t)row * OUT_CH + cc] : 0.f;
  }
  __syncthreads();
  const float b0 = bd[c];
  for (int i = 0; i < 64; i++) {
    int row = n0 + i;
    if (row >= N_NODES) break;
    float a0 = b0;
#pragma unroll
    for (int k4 = 0; k4 < 8; k4++) {
      float4 zv = *(const float4*)&zs[i][k4 * 4];
      a0 += zv.x * wd[k4 * 4 + 0] + zv.y * wd[k4 * 4 + 1] +
            zv.z * wd[k4 * 4 + 2] + zv.w * wd[k4 * 4 + 3];
    }
    xhat[(size_t)row * IN_CH + c] = a0;
  }
}

// ----------------------------------------------------------------------------
extern "C" void kernel_launch(void* const* d_in, const int* in_sizes, int n_in,
                              void* d_out, int out_size, void* d_ws, size_t ws_size,
                              hipStream_t stream) {
  const float* x    = (const float*)d_in[0];
  const int*   ei   = (const int*)d_in[1];
  const float* W1   = (const float*)d_in[2];
  const float* a_s1 = (const float*)d_in[3];
  const float* a_d1 = (const float*)d_in[4];
  const float* b1   = (const float*)d_in[5];
  const float* W2   = (const float*)d_in[6];
  const float* a_s2 = (const float*)d_in[7];
  const float* a_d2 = (const float*)d_in[8];
  const float* b2   = (const float*)d_in[9];
  const float* Wd   = (const float*)d_in[10];
  const float* bd   = (const float*)d_in[11];

  float* xhat = (float*)d_out;
  float* zout = xhat + (size_t)N_NODES * IN_CH;

  const int* srcv = ei;
  const int* dstv = ei + N_EDGES;

  char* w = (char*)d_ws;
  auto alloc = [&](size_t bytes) {
    void* p = (void*)w;
    w += (bytes + 255) & ~(size_t)255;
    return p;
  };
  _Float16* xh   = (_Float16*)alloc((size_t)M_PAD * IN_CH * 2);
  _Float16* w1t  = (_Float16*)alloc((size_t)HC * IN_CH * 2);
  _Float16* w2t  = (_Float16*)alloc((size_t)32 * HC * 2);
  _Float16* h    = (_Float16*)alloc((size_t)N_NODES * HC * 2);
  _Float16* hm   = (_Float16*)alloc((size_t)N_NODES * HC * 2);
  float* zpre  = (float*)alloc((size_t)N_NODES * OUT_CH * 4);
  float* al_s1v= (float*)alloc((size_t)N_NODES * HEADS * 4);
  float* al_d1v= (float*)alloc((size_t)N_NODES * HEADS * 4);
  float* al_s2v= (float*)alloc((size_t)N_NODES * 4);
  float* al_d2v= (float*)alloc((size_t)N_NODES * 4);
  int*   cnt   = (int*)alloc((size_t)N_NODES * 4);
  int*   offs  = (int*)alloc((size_t)(N_NODES + 1) * 4);
  int*   cursor= (int*)alloc((size_t)N_NODES * 4);
  int*   srcs  = (int*)alloc((size_t)N_EDGES * 4);
  int*   part  = (int*)alloc((size_t)PARTS * 4);

  const int EB = (N_EDGES + 255) / 256;

  k_prep_w<<<128, 256, 0, stream>>>(W1, W2, w1t, w2t);
  k_cast_x<<<M_PAD * IN_CH / 4 / 256, 256, 0, stream>>>(x, xh, cnt);
  k_gemm1_mfma<<<dim3(M_PAD / 128, HC / 128), 256, 0, stream>>>(xh, w1t, h, a_s1, a_d1,
                                                                al_s1v, al_d1v);
  // CSR build
  k_count<<<EB, 256, 0, stream>>>(dstv, cnt);
  k_scan_part<<<PARTS, 256, 0, stream>>>(cnt, part);
  k_scan_tops<<<1, 128, 0, stream>>>(part, offs);
  k_scan_final<<<PARTS, 256, 0, stream>>>(cnt, part, offs, cursor);
  k_scatter<<<EB, 256, 0, stream>>>(srcv, dstv, cursor, srcs);
  // aggregate layer 1: quarter-wave per node, 4 sequential head passes
  k_agg1<<<1250 * HEADS, 256, 0, stream>>>(h, al_s1v, al_d1v, offs, srcs, b1, hm);
  // GEMM2 (MFMA) + fused layer-2 logits
  k_gemm2_mfma<<<(N_NODES + 63) / 64, 256, 0, stream>>>(hm, w2t, a_s2, a_d2, zpre,
                                                        al_s2v, al_d2v);
  // aggregate layer 2 -> z
  k_agg2<<<N_NODES / 8, 256, 0, stream>>>(zpre, al_s2v, al_d2v, offs, srcs, b2, zout);
  // decoder
  k_dec<<<dim3((N_NODES + 63) / 64, 2), 256, 0, stream>>>(zout, Wd, bd, xhat);
}

// Round 8
// 256.386 us; speedup vs baseline: 2.6036x; 1.0414x over previous
//
#include <hip/hip_runtime.h>
#include <hip/hip_bf16.h>
#include <stdint.h>

#define N_NODES 20000
#define N_EDGES 320000
#define IN_CH 512
#define HID 128
#define HEADS 4
#define HC 512          // HEADS*HID
#define OUT_CH 30
#define NEG_SLOPE 0.2f
#define M_PAD 20096     // 157 * 128
#define PARTS 79        // ceil(20000/256)
#define CAST_BLOCKS (M_PAD * IN_CH / 4 / 256)   // 10048
#define G1_BLOCKS (M_PAD / 128 * 4)             // 628
#define CNT_BLOCKS (N_EDGES / 256)              // 1250

typedef _Float16 half8 __attribute__((ext_vector_type(8)));
typedef _Float16 half4v __attribute__((ext_vector_type(4)));
typedef float f32x4 __attribute__((ext_vector_type(4)));

static __device__ __forceinline__ float lrelu(float e) { return e > 0.f ? e : NEG_SLOPE * e; }

// async global->LDS, 16B per lane; dest = wave-uniform base + lane*16
static __device__ __forceinline__ void gload16(const void* gsrc, void* ldst) {
  __builtin_amdgcn_global_load_lds(
      (const __attribute__((address_space(1))) uint32_t*)gsrc,
      (__attribute__((address_space(3))) uint32_t*)ldst,
      16, 0, 0);
}

// ---- front kernel: cast x->fp16 (+zero cnt), W1->w1t fp16, W2->w2t fp16 ----
__global__ __launch_bounds__(256) void k_front(const float* __restrict__ x,
                                               const float* __restrict__ W1,
                                               const float* __restrict__ W2,
                                               _Float16* __restrict__ xh,
                                               _Float16* __restrict__ W1t,
                                               _Float16* __restrict__ w2t,
                                               int* __restrict__ cnt) {
  __shared__ float t[64][65];
  const int b = blockIdx.x;
  const int tid = threadIdx.x;
  if (b < CAST_BLOCKS) {
    int i = b * 256 + tid;
    if (i < N_NODES) cnt[i] = 0;
    int base = i * 4;
    int row = base >> 9;
    half4v o;
    if (row < N_NODES) {
      float4 v = *(const float4*)(x + (size_t)base);
      o[0] = (_Float16)v.x; o[1] = (_Float16)v.y; o[2] = (_Float16)v.z; o[3] = (_Float16)v.w;
    } else {
      o[0] = o[1] = o[2] = o[3] = (_Float16)0.f;
    }
    *(half4v*)(xh + (size_t)base) = o;
  } else if (b < CAST_BLOCKS + 64) {
    const int bb = b - CAST_BLOCKS;
    const int bk = (bb & 7) * 64;
    const int bn = (bb >> 3) * 64;
#pragma unroll
    for (int it = 0; it < 16; it++) {
      int idx = tid + it * 256;
      int r = idx >> 6, c = idx & 63;
      t[r][c] = W1[(size_t)(bk + r) * HC + bn + c];
    }
    __syncthreads();
#pragma unroll
    for (int it = 0; it < 16; it++) {
      int idx = tid + it * 256;
      int rn = idx >> 6, ck = idx & 63;
      W1t[(size_t)(bn + rn) * IN_CH + bk + ck] = (_Float16)t[ck][rn];
    }
  } else {
    int idx = (b - CAST_BLOCKS - 64) * 256 + tid;   // over 32*512
    int n = idx >> 9, k = idx & 511;
    w2t[idx] = (n < OUT_CH) ? (_Float16)W2[(size_t)k * OUT_CH + n] : (_Float16)0.f;
  }
}

// ---- GEMM1 (MFMA fp16) + fused layer-1 logits + fused degree count ---------
// blocks [0,628): gemm tiles (m=bx>>2, head=bx&3); blocks [628,1878): count.
__global__ __launch_bounds__(256) void k_gemm1_mfma(const _Float16* __restrict__ A,
                                                    const _Float16* __restrict__ Bt,
                                                    _Float16* __restrict__ C,
                                                    const float* __restrict__ a_src,
                                                    const float* __restrict__ a_dst,
                                                    float* __restrict__ al_s,
                                                    float* __restrict__ al_d,
                                                    const int* __restrict__ dst,
                                                    int* __restrict__ cnt) {
  __shared__ _Float16 smem[128 * 136];   // 34816 B
  const int bx = blockIdx.x;
  const int tid = threadIdx.x;
  if (bx >= G1_BLOCKS) {                  // fused degree count
    int e = (bx - G1_BLOCKS) * 256 + tid;
    if (e < N_EDGES) atomicAdd(&cnt[dst[e]], 1);
    return;
  }
  _Float16* As = smem;                    // 128*64
  _Float16* Bs = smem + 128 * 64;         // 128*64
  _Float16* Cs = smem;                    // reused after final barrier
  const int lane = tid & 63;
  const int w = tid >> 6;
  const int bm = (bx >> 2) * 128;
  const int head = bx & 3;
  const int bn = head * 128;

  const int lrow = lane >> 3;
  const int schunk = (lane & 7) ^ lrow;

  const int wm = w >> 1, wn = w & 1;
  const int r15 = lane & 15;
  const int q = lane >> 4;
  const int a_row0 = wm * 64 + r15;
  const int b_row0 = wn * 64 + r15;

  f32x4 acc[4][4];
  const f32x4 zero = {0.f, 0.f, 0.f, 0.f};
#pragma unroll
  for (int i = 0; i < 4; i++)
#pragma unroll
    for (int j = 0; j < 4; j++) acc[i][j] = zero;

  for (int kb = 0; kb < 8; kb++) {
    const int kof = kb * 64 + schunk * 8;
#pragma unroll
    for (int t = 0; t < 4; t++) {
      const int row = w * 32 + t * 8;
      gload16(A + (size_t)(bm + row + lrow) * IN_CH + kof, (void*)(As + row * 64));
      gload16(Bt + (size_t)(bn + row + lrow) * IN_CH + kof, (void*)(Bs + row * 64));
    }
    __syncthreads();
#pragma unroll
    for (int s = 0; s < 2; s++) {
      const int cs = ((s * 4 + q) ^ (lane & 7)) * 8;
      half8 af[4], bf[4];
#pragma unroll
      for (int i = 0; i < 4; i++) af[i] = *(const half8*)&As[(a_row0 + i * 16) * 64 + cs];
#pragma unroll
      for (int j = 0; j < 4; j++) bf[j] = *(const half8*)&Bs[(b_row0 + j * 16) * 64 + cs];
#pragma unroll
      for (int i = 0; i < 4; i++)
#pragma unroll
        for (int j = 0; j < 4; j++)
          acc[i][j] = __builtin_amdgcn_mfma_f32_16x16x32_f16(af[i], bf[j], acc[i][j], 0, 0, 0);
    }
    __syncthreads();
  }
  // epilogue: bounce through LDS, coalesced half8 stores
#pragma unroll
  for (int i = 0; i < 4; i++)
#pragma unroll
    for (int j = 0; j < 4; j++)
#pragma unroll
      for (int r = 0; r < 4; r++) {
        const int row = wm * 64 + i * 16 + q * 4 + r;
        const int col = wn * 64 + j * 16 + r15;
        Cs[row * 136 + col] = (_Float16)acc[i][j][r];
      }
  __syncthreads();
#pragma unroll
  for (int it = 0; it < 8; it++) {
    int cidx = tid + it * 256;
    int row = cidx >> 4, c16 = cidx & 15;
    int gm = bm + row;
    if (gm < N_NODES)
      *(half8*)(C + (size_t)gm * HC + bn + c16 * 8) = *(const half8*)&Cs[row * 136 + c16 * 8];
  }
  // fused al1: this block's 128 cols == head slice. 2 threads/row, 64 cols each.
  const int row = tid >> 1;
  const int hf = tid & 1;
  const float* asp = a_src + head * HID + hf * 64;
  const float* adp = a_dst + head * HID + hf * 64;
  float s = 0.f, d = 0.f;
#pragma unroll
  for (int j8 = 0; j8 < 8; j8++) {
    half8 cv = *(const half8*)&Cs[row * 136 + hf * 64 + j8 * 8];
    float4 a0 = *(const float4*)(asp + j8 * 8);
    float4 a1 = *(const float4*)(asp + j8 * 8 + 4);
    float4 d0 = *(const float4*)(adp + j8 * 8);
    float4 d1 = *(const float4*)(adp + j8 * 8 + 4);
    float c0 = (float)cv[0], c1 = (float)cv[1], c2 = (float)cv[2], c3 = (float)cv[3];
    float c4 = (float)cv[4], c5 = (float)cv[5], c6 = (float)cv[6], c7 = (float)cv[7];
    s += c0 * a0.x + c1 * a0.y + c2 * a0.z + c3 * a0.w +
         c4 * a1.x + c5 * a1.y + c6 * a1.z + c7 * a1.w;
    d += c0 * d0.x + c1 * d0.y + c2 * d0.z + c3 * d0.w +
         c4 * d1.x + c5 * d1.y + c6 * d1.z + c7 * d1.w;
  }
  s += __shfl_xor(s, 1);
  d += __shfl_xor(d, 1);
  const int gm = bm + row;
  if (hf == 0 && gm < N_NODES) {
    al_s[gm * HEADS + head] = s;
    al_d[gm * HEADS + head] = d;
  }
}

// ------------------------------- CSR build ----------------------------------
__global__ __launch_bounds__(256) void k_scan_part(const int* __restrict__ cnt,
                                                   int* __restrict__ part) {
  __shared__ int ws[4];
  int i = blockIdx.x * 256 + threadIdx.x;
  int v = (i < N_NODES) ? cnt[i] : 0;
  int lane = threadIdx.x & 63;
#pragma unroll
  for (int off = 32; off; off >>= 1) v += __shfl_down(v, off);
  if (lane == 0) ws[threadIdx.x >> 6] = v;
  __syncthreads();
  if (threadIdx.x == 0) part[blockIdx.x] = ws[0] + ws[1] + ws[2] + ws[3];
}
// each block computes its own prefix over part[] with one wave (kills scan_tops)
__global__ __launch_bounds__(256) void k_scan_final(const int* __restrict__ cnt,
                                                    const int* __restrict__ part,
                                                    int* __restrict__ offs,
                                                    int* __restrict__ cursor) {
  __shared__ int buf[256];
  __shared__ int s_prefix;
  const int b = blockIdx.x;
  const int t = threadIdx.x;
  if (t < 64) {
    int v = 0;
    for (int j = t; j < b; j += 64) v += part[j];
#pragma unroll
    for (int off = 32; off; off >>= 1) v += __shfl_down(v, off);
    if (t == 0) s_prefix = v;
  }
  int i = b * 256 + t;
  int v = (i < N_NODES) ? cnt[i] : 0;
  buf[t] = v;
  __syncthreads();
#pragma unroll
  for (int off = 1; off < 256; off <<= 1) {
    int x = (t >= off) ? buf[t - off] : 0;
    __syncthreads();
    buf[t] += x;
    __syncthreads();
  }
  if (i < N_NODES) {
    int ex = s_prefix + buf[t] - v;
    offs[i] = ex;
    cursor[i] = ex;
  }
  if (b == PARTS - 1 && t == 255) offs[N_NODES] = s_prefix + buf[255];
}
__global__ void k_scatter(const int* __restrict__ src, const int* __restrict__ dst,
                          int* __restrict__ cursor, int* __restrict__ srcs) {
  int e = blockIdx.x * blockDim.x + threadIdx.x;
  if (e < N_EDGES) {
    int pos = atomicAdd(&cursor[dst[e]], 1);
    srcs[pos] = src[e];
  }
}

// ---- agg layer 1: quarter-wave/node, LDS b128 meta broadcast, 4-deep ILP ---
__global__ __launch_bounds__(256) void k_agg1(const _Float16* __restrict__ h,
                                              const float* __restrict__ al_s,
                                              const float* __restrict__ al_d,
                                              const int* __restrict__ offs,
                                              const int* __restrict__ srcs,
                                              const float* __restrict__ b1,
                                              _Float16* __restrict__ hm) {
  __shared__ __align__(16) int2 s_sp[4][64];
  const int tid = threadIdx.x;
  const int lane = tid & 63;
  const int wv = tid >> 6;
  const int qq = lane >> 4;                // quarter = node within wave
  const int l16 = lane & 15;
  const int head = blockIdx.x / 1250;      // head-major: L2-resident slice pass
  const int n = (blockIdx.x % 1250) * 16 + wv * 4 + qq;
  const int cb = head * HID + l16 * 8;

  const float adn = al_d[n * HEADS + head];
  const float pself = __expf(lrelu(al_s[n * HEADS + head] + adn));

  half8 hv = *(const half8*)(h + (size_t)n * HC + cb);
  float acc[8];
  float den = pself;
#pragma unroll
  for (int j = 0; j < 8; j++) acc[j] = pself * (float)hv[j];

  const int beg = offs[n];
  const int cnt = offs[n + 1] - beg;
  int mx = cnt;
  mx = max(mx, __shfl_xor(mx, 16));
  mx = max(mx, __shfl_xor(mx, 32));

  for (int base = 0; base < mx; base += 16) {
    // stage this lane's edge (branchless; invalid -> p=0, s=n harmless)
    int sreg = n;
    float preg = 0.f;
    if (base + l16 < cnt) {
      sreg = srcs[beg + base + l16];
      preg = __expf(lrelu(al_s[sreg * HEADS + head] + adn));
    }
    s_sp[wv][lane] = make_int2(sreg, __float_as_int(preg));
    __builtin_amdgcn_wave_barrier();
    const int rem = cnt - base;
    const int m4 = rem > 16 ? 16 : ((rem + 3) & ~3);   // <=0 skips loop
    for (int k = 0; k < m4; k += 4) {
      int4 w0 = *(const int4*)&s_sp[wv][qq * 16 + k];      // broadcast b128
      int4 w1 = *(const int4*)&s_sp[wv][qq * 16 + k + 2];
      half8 v0 = *(const half8*)(h + (size_t)w0.x * HC + cb);
      half8 v1 = *(const half8*)(h + (size_t)w0.z * HC + cb);
      half8 v2 = *(const half8*)(h + (size_t)w1.x * HC + cb);
      half8 v3 = *(const half8*)(h + (size_t)w1.z * HC + cb);
      float p0 = __int_as_float(w0.y), p1 = __int_as_float(w0.w);
      float p2 = __int_as_float(w1.y), p3 = __int_as_float(w1.w);
      den += p0 + p1 + p2 + p3;
#pragma unroll
      for (int j = 0; j < 8; j++)
        acc[j] += p0 * (float)v0[j] + p1 * (float)v1[j] +
                  p2 * (float)v2[j] + p3 * (float)v3[j];
    }
    __builtin_amdgcn_wave_barrier();
  }
  const float inv = 1.f / den;
  float4 bb0 = *(const float4*)(b1 + cb);
  float4 bb1 = *(const float4*)(b1 + cb + 4);
  float ob[8] = {bb0.x, bb0.y, bb0.z, bb0.w, bb1.x, bb1.y, bb1.z, bb1.w};
  half8 ov;
#pragma unroll
  for (int j = 0; j < 8; j++) {
    float o = acc[j] * inv + ob[j];
    o = o > 0.f ? o : __expf(o) - 1.f;      // ELU
    ov[j] = (_Float16)o;
  }
  *(half8*)(hm + (size_t)n * HC + cb) = ov;
}

// ------- GEMM2 (MFMA fp16) + fused layer-2 logits: zpre = hm @ W2 -----------
__global__ __launch_bounds__(256) void k_gemm2_mfma(const _Float16* __restrict__ hm,
                                                    const _Float16* __restrict__ w2t,
                                                    const float* __restrict__ a_s2,
                                                    const float* __restrict__ a_d2,
                                                    float* __restrict__ zpre,
                                                    float* __restrict__ al_s2,
                                                    float* __restrict__ al_d2) {
  __shared__ _Float16 Bs[32 * 520];
  __shared__ _Float16 As[64 * 136];
  const int tid = threadIdx.x;
  const int lane = tid & 63;
  const int w = tid >> 6;
  const int bm = blockIdx.x * 64;
  const int n15 = lane & 15;
  const int q = lane >> 4;

#pragma unroll
  for (int it = 0; it < 8; it++) {
    int idx = (tid + it * 256) * 8;
    int n = idx >> 9, k = idx & 511;
    *(half8*)&Bs[n * 520 + k] = *(const half8*)(w2t + idx);
  }

  f32x4 acc0 = {0.f, 0.f, 0.f, 0.f}, acc1 = {0.f, 0.f, 0.f, 0.f};
  for (int kt = 0; kt < HC; kt += 128) {
#pragma unroll
    for (int p = 0; p < 4; p++) {
      int row = (tid >> 4) + p * 16;
      int kof = (tid & 15) * 8;
      int gm = bm + row;
      half8 v = {};
      if (gm < N_NODES) v = *(const half8*)(hm + (size_t)gm * HC + kt + kof);
      *(half8*)&As[row * 136 + kof] = v;
    }
    __syncthreads();
#pragma unroll
    for (int ks = 0; ks < 128; ks += 32) {
      half8 af = *(const half8*)&As[(w * 16 + n15) * 136 + ks + q * 8];
      half8 b0 = *(const half8*)&Bs[n15 * 520 + kt + ks + q * 8];
      half8 b1 = *(const half8*)&Bs[(16 + n15) * 520 + kt + ks + q * 8];
      acc0 = __builtin_amdgcn_mfma_f32_16x16x32_f16(af, b0, acc0, 0, 0, 0);
      acc1 = __builtin_amdgcn_mfma_f32_16x16x32_f16(af, b1, acc1, 0, 0, 0);
    }
    __syncthreads();
  }
  const float asn0 = (n15 < OUT_CH) ? a_s2[n15] : 0.f;
  const float asn1 = (n15 + 16 < OUT_CH) ? a_s2[n15 + 16] : 0.f;
  const float adn0 = (n15 < OUT_CH) ? a_d2[n15] : 0.f;
  const float adn1 = (n15 + 16 < OUT_CH) ? a_d2[n15 + 16] : 0.f;
#pragma unroll
  for (int r = 0; r < 4; r++) {
    const int gm = bm + w * 16 + q * 4 + r;
    const bool ok = gm < N_NODES;
    if (ok) {
      zpre[(size_t)gm * OUT_CH + n15] = acc0[r];
      if (n15 + 16 < OUT_CH) zpre[(size_t)gm * OUT_CH + n15 + 16] = acc1[r];
    }
    float s = acc0[r] * asn0 + acc1[r] * asn1;
    float d = acc0[r] * adn0 + acc1[r] * adn1;
#pragma unroll
    for (int off = 8; off; off >>= 1) {
      s += __shfl_xor(s, off);
      d += __shfl_xor(d, off);
    }
    if (n15 == 0 && ok) {
      al_s2[gm] = s;
      al_d2[gm] = d;
    }
  }
}

// ---- agg layer 2: half-wave/node, LDS b128 meta broadcast, 4-deep ILP ------
__global__ __launch_bounds__(256) void k_agg2(const float* __restrict__ zpre,
                                              const float* __restrict__ al_s2,
                                              const float* __restrict__ al_d2,
                                              const int* __restrict__ offs,
                                              const int* __restrict__ srcs,
                                              const float* __restrict__ b2,
                                              float* __restrict__ zout) {
  __shared__ __align__(16) int2 s_sp[4][64];
  const int tid = threadIdx.x;
  const int lane = tid & 63;
  const int wv = tid >> 6;
  const int hh = lane >> 5;
  const int l32 = lane & 31;
  const int n = blockIdx.x * 8 + wv * 2 + hh;  // grid 2500 -> exactly 20000
  const float ad2n = al_d2[n];
  const float pself = __expf(lrelu(al_s2[n] + ad2n));
  const bool act = l32 < OUT_CH;
  float zv = act ? zpre[(size_t)n * OUT_CH + l32] : 0.f;
  float acc = pself * zv;
  float den = pself;

  const int beg = offs[n];
  const int cnt = offs[n + 1] - beg;
  int mx = max(cnt, __shfl_xor(cnt, 32));

  for (int base = 0; base < mx; base += 32) {
    int sreg = n;
    float preg = 0.f;
    if (base + l32 < cnt) {
      sreg = srcs[beg + base + l32];
      preg = __expf(lrelu(al_s2[sreg] + ad2n));
    }
    s_sp[wv][lane] = make_int2(sreg, __float_as_int(preg));
    __builtin_amdgcn_wave_barrier();
    const int rem = cnt - base;
    const int m4 = rem > 32 ? 32 : ((rem + 3) & ~3);
    for (int k = 0; k < m4; k += 4) {
      int4 w0 = *(const int4*)&s_sp[wv][hh * 32 + k];
      int4 w1 = *(const int4*)&s_sp[wv][hh * 32 + k + 2];
      float v0 = act ? zpre[(size_t)w0.x * OUT_CH + l32] : 0.f;
      float v1 = act ? zpre[(size_t)w0.z * OUT_CH + l32] : 0.f;
      float v2 = act ? zpre[(size_t)w1.x * OUT_CH + l32] : 0.f;
      float v3 = act ? zpre[(size_t)w1.z * OUT_CH + l32] : 0.f;
      float p0 = __int_as_float(w0.y), p1 = __int_as_float(w0.w);
      float p2 = __int_as_float(w1.y), p3 = __int_as_float(w1.w);
      den += p0 + p1 + p2 + p3;
      acc += p0 * v0 + p1 * v1 + p2 * v2 + p3 * v3;
    }
    __builtin_amdgcn_wave_barrier();
  }
  if (act) zout[(size_t)n * OUT_CH + l32] = acc / den + b2[l32];
}

// ------- decoder: x_hat = z @ Wd + bd, 64 rows x 256 cols per block ---------
__global__ __launch_bounds__(256) void k_dec(const float* __restrict__ z,
                                             const float* __restrict__ Wd,
                                             const float* __restrict__ bd,
                                             float* __restrict__ xhat) {
  __shared__ float zs[64][32];
  const int tid = threadIdx.x;
  const int c = blockIdx.y * 256 + tid;   // one column per thread
  float wd[32];
#pragma unroll
  for (int k = 0; k < OUT_CH; k++) wd[k] = Wd[(size_t)k * IN_CH + c];
  wd[30] = wd[31] = 0.f;
  const int n0 = blockIdx.x * 64;
  for (int idx = tid; idx < 64 * 32; idx += 256) {
    int r = idx >> 5, cc = idx & 31;
    int row = n0 + r;
    zs[r][cc] = (cc < OUT_CH && row < N_NODES) ? z[(size_t)row * OUT_CH + cc] : 0.f;
  }
  __syncthreads();
  const float b0 = bd[c];
  for (int i = 0; i < 64; i++) {
    int row = n0 + i;
    if (row >= N_NODES) break;
    float a0 = b0;
#pragma unroll
    for (int k4 = 0; k4 < 8; k4++) {
      float4 zv = *(const float4*)&zs[i][k4 * 4];
      a0 += zv.x * wd[k4 * 4 + 0] + zv.y * wd[k4 * 4 + 1] +
            zv.z * wd[k4 * 4 + 2] + zv.w * wd[k4 * 4 + 3];
    }
    xhat[(size_t)row * IN_CH + c] = a0;
  }
}

// ----------------------------------------------------------------------------
extern "C" void kernel_launch(void* const* d_in, const int* in_sizes, int n_in,
                              void* d_out, int out_size, void* d_ws, size_t ws_size,
                              hipStream_t stream) {
  const float* x    = (const float*)d_in[0];
  const int*   ei   = (const int*)d_in[1];
  const float* W1   = (const float*)d_in[2];
  const float* a_s1 = (const float*)d_in[3];
  const float* a_d1 = (const float*)d_in[4];
  const float* b1   = (const float*)d_in[5];
  const float* W2   = (const float*)d_in[6];
  const float* a_s2 = (const float*)d_in[7];
  const float* a_d2 = (const float*)d_in[8];
  const float* b2   = (const float*)d_in[9];
  const float* Wd   = (const float*)d_in[10];
  const float* bd   = (const float*)d_in[11];

  float* xhat = (float*)d_out;
  float* zout = xhat + (size_t)N_NODES * IN_CH;

  const int* srcv = ei;
  const int* dstv = ei + N_EDGES;

  char* w = (char*)d_ws;
  auto alloc = [&](size_t bytes) {
    void* p = (void*)w;
    w += (bytes + 255) & ~(size_t)255;
    return p;
  };
  _Float16* xh   = (_Float16*)alloc((size_t)M_PAD * IN_CH * 2);
  _Float16* w1t  = (_Float16*)alloc((size_t)HC * IN_CH * 2);
  _Float16* w2t  = (_Float16*)alloc((size_t)32 * HC * 2);
  _Float16* h    = (_Float16*)alloc((size_t)N_NODES * HC * 2);
  _Float16* hm   = (_Float16*)alloc((size_t)N_NODES * HC * 2);
  float* zpre  = (float*)alloc((size_t)N_NODES * OUT_CH * 4);
  float* al_s1v= (float*)alloc((size_t)N_NODES * HEADS * 4);
  float* al_d1v= (float*)alloc((size_t)N_NODES * HEADS * 4);
  float* al_s2v= (float*)alloc((size_t)N_NODES * 4);
  float* al_d2v= (float*)alloc((size_t)N_NODES * 4);
  int*   cnt   = (int*)alloc((size_t)N_NODES * 4);
  int*   offs  = (int*)alloc((size_t)(N_NODES + 1) * 4);
  int*   cursor= (int*)alloc((size_t)N_NODES * 4);
  int*   srcs  = (int*)alloc((size_t)N_EDGES * 4);
  int*   part  = (int*)alloc((size_t)PARTS * 4);

  const int EB = (N_EDGES + 255) / 256;

  // 1: casts + cnt zero
  k_front<<<CAST_BLOCKS + 128, 256, 0, stream>>>(x, W1, W2, xh, w1t, w2t, cnt);
  // 2: GEMM1 + fused al1 + fused degree count
  k_gemm1_mfma<<<G1_BLOCKS + CNT_BLOCKS, 256, 0, stream>>>(xh, w1t, h, a_s1, a_d1,
                                                           al_s1v, al_d1v, dstv, cnt);
  // 3-5: CSR scan + scatter
  k_scan_part<<<PARTS, 256, 0, stream>>>(cnt, part);
  k_scan_final<<<PARTS, 256, 0, stream>>>(cnt, part, offs, cursor);
  k_scatter<<<EB, 256, 0, stream>>>(srcv, dstv, cursor, srcs);
  // 6: aggregate layer 1 (4 head passes)
  k_agg1<<<1250 * HEADS, 256, 0, stream>>>(h, al_s1v, al_d1v, offs, srcs, b1, hm);
  // 7: GEMM2 + fused layer-2 logits
  k_gemm2_mfma<<<(N_NODES + 63) / 64, 256, 0, stream>>>(hm, w2t, a_s2, a_d2, zpre,
                                                        al_s2v, al_d2v);
  // 8: aggregate layer 2 -> z
  k_agg2<<<N_NODES / 8, 256, 0, stream>>>(zpre, al_s2v, al_d2v, offs, srcs, b2, zout);
  // 9: decoder
  k_dec<<<dim3((N_NODES + 63) / 64, 2), 256, 0, stream>>>(zout, Wd, bd, xhat);
}